// Round 4
// baseline (540.787 us; speedup 1.0000x reference)
//
#include <hip/hip_runtime.h>
#include <math.h>

typedef unsigned short u16;
typedef __bf16 bf16x8 __attribute__((ext_vector_type(8)));
typedef float f32x4 __attribute__((ext_vector_type(4)));

#define NPACK  11264   // padded packed-pair count (88*128)
#define NVALID 10864   // 8256 + 2080 + 528
#define BASE1  8256
#define BASE2  10336

__device__ __forceinline__ u16 f2bf(float f) {
    unsigned u = __builtin_bit_cast(unsigned, f);
    u += 0x7FFFu + ((u >> 16) & 1u);
    return (u16)(u >> 16);
}
__device__ __forceinline__ float bf2f(u16 h) {
    return __builtin_bit_cast(float, ((unsigned)h) << 16);
}

#define GLOAD_LDS16(g, l)                                                     \
    __builtin_amdgcn_global_load_lds(                                         \
        (const __attribute__((address_space(1))) void*)(g),                   \
        (__attribute__((address_space(3))) void*)(l), 16, 0, 0)

// packed triangular index (u<=v), per segment
__device__ __forceinline__ int pk0(int a, int b) {
    int u = min(a, b), v = max(a, b);
    return u * 128 - (u * (u - 1)) / 2 + (v - u);
}
__device__ __forceinline__ int pk1(int a, int b) {
    int u = min(a, b), v = max(a, b);
    return BASE1 + u * 64 - (u * (u - 1)) / 2 + (v - u);
}
__device__ __forceinline__ int pk2(int a, int b) {
    int u = min(a, b), v = max(a, b);
    return BASE2 + u * 32 - (u * (u - 1)) / 2 + (v - u);
}

// ---------------------------------------------------------------- uv table (one launch)
__global__ __launch_bounds__(256) void k_uvall(u16* __restrict__ tab) {
    int j = blockIdx.x * 256 + threadIdx.x;
    if (j < 16384) {
        int u = j >> 7, v = j & 127;
        if (v >= u) tab[pk0(u, v)] = (u16)((u << 7) | v);
    } else if (j < 20480) {
        int k = j - 16384, u = k >> 6, v = k & 63;
        if (v >= u) tab[pk1(u, v)] = (u16)((1 << 14) | (u << 7) | v);
    } else if (j < 21504) {
        int k = j - 20480, u = k >> 5, v = k & 31;
        if (v >= u) tab[pk2(u, v)] = (u16)((2 << 14) | (u << 7) | v);
    } else {
        int k = j - 21504;
        if (NVALID + k < NPACK) tab[NVALID + k] = 0xFFFFu;
    }
}

// ---------------------------------------------------------------- packed weights
__global__ __launch_bounds__(256) void k_packw(const float* __restrict__ w0,
                                               const float* __restrict__ w1,
                                               const float* __restrict__ w2,
                                               const u16* __restrict__ tab,
                                               u16* __restrict__ Wsym,
                                               u16* __restrict__ Wt) {
    __shared__ u16 tile[32][258];
    __shared__ u16 te[32];
    int i0 = blockIdx.x * 32, h0 = blockIdx.y * 256, tid = threadIdx.x;
    if (tid < 32) te[tid] = tab[i0 + tid];
    __syncthreads();
    const float s1 = 0.57735026918962576f, s2 = 0.44721359549995794f;
    for (int il = 0; il < 32; il++) {
        unsigned e = te[il];
        float val = 0.f;
        if ((e >> 14) != 3) {
            int seg = e >> 14, u = (e >> 7) & 127, v = e & 127;
            const float* wb; int S; float sc;
            if (seg == 0)      { wb = w0; S = 128; sc = 1.f; }
            else if (seg == 1) { wb = w1; S = 64;  sc = s1; }
            else               { wb = w2; S = 32;  sc = s2; }
            val = sc * (wb[(size_t)(u * S + v) * 1024 + h0 + tid] +
                        wb[(size_t)(v * S + u) * 1024 + h0 + tid]);
        }
        u16 bv = f2bf(val);
        Wsym[(size_t)(i0 + il) * 1024 + h0 + tid] = bv;
        tile[il][tid] = bv;
    }
    __syncthreads();
    union { u16 a[32]; uint4 q[4]; } pk;
#pragma unroll
    for (int il = 0; il < 32; il++) pk.a[il] = tile[il][tid];
    uint4* dst = (uint4*)(Wt + (size_t)(h0 + tid) * NPACK + i0);
#pragma unroll
    for (int q = 0; q < 4; q++) dst[q] = pk.q[q];
}

// ---------------------------------------------------------------- converts
__global__ __launch_bounds__(256) void k_convert(const float* __restrict__ in,
                                                 u16* __restrict__ out, int n4) {
    int i = blockIdx.x * 256 + threadIdx.x;
    if (i >= n4) return;
    float4 v = ((const float4*)in)[i];
    union { u16 a[4]; unsigned long long q; } o;
    o.a[0] = f2bf(v.x); o.a[1] = f2bf(v.y); o.a[2] = f2bf(v.z); o.a[3] = f2bf(v.w);
    ((unsigned long long*)out)[i] = o.q;
}

__global__ __launch_bounds__(256) void k_transpose(const float* __restrict__ in, int R, int C,
                                                   u16* __restrict__ out, int ldOut) {
    __shared__ float tile[32][33];
    int tr0 = blockIdx.y * 32;
    int tc0 = blockIdx.x * 32;
    int lr = threadIdx.x >> 5;
    int lc = threadIdx.x & 31;
#pragma unroll
    for (int i = 0; i < 4; i++) {
        int rr = lr + i * 8;
        tile[rr][lc] = in[(size_t)(tr0 + rr) * C + tc0 + lc];
    }
    __syncthreads();
#pragma unroll
    for (int i = 0; i < 4; i++) {
        int rr = lr + i * 8;
        out[(size_t)(tc0 + rr) * ldOut + tr0 + lc] = f2bf(tile[lc][rr]);
    }
}

// ---------------------------------------------------------------- packed features
__global__ __launch_bounds__(256) void k_features_pack(const float* __restrict__ t,
                                                       const u16* __restrict__ tab,
                                                       u16* __restrict__ P) {
    __shared__ u16 tab_s[NPACK];
    __shared__ float tr[480];
    int b = blockIdx.x, tid = threadIdx.x;
    for (int j = tid; j < NPACK / 8; j += 256)
        ((uint4*)tab_s)[j] = ((const uint4*)tab)[j];
    for (int j = tid; j < 480; j += 256) tr[j] = t[(size_t)b * 480 + j];
    __syncthreads();
    u16* row = P + (size_t)b * NPACK;
    for (int i = tid; i < NPACK; i += 256) {
        unsigned e = tab_s[i];
        float p = 0.f;
        if ((e >> 14) != 3) {
            int seg = e >> 14, u = (e >> 7) & 127, v = e & 127;
            if (seg == 0) p = tr[u] * tr[v];
            else if (seg == 1) {
                const float* x1 = tr + 128;
                p = x1[u*3]*x1[v*3] + x1[u*3+1]*x1[v*3+1] + x1[u*3+2]*x1[v*3+2];
            } else {
                const float* x2 = tr + 320;
#pragma unroll
                for (int m = 0; m < 5; m++) p += x2[u*5+m] * x2[v*5+m];
            }
            if (u == v) p *= 0.5f;
        }
        row[i] = f2bf(p);
    }
}

// ---------------------------------------------------------------- GEMM 128-tile (round-0, MLP sizes)
__global__ __launch_bounds__(256) void k_gemm2(const u16* __restrict__ A, int ldA,
                                               const u16* __restrict__ B, int ldB,
                                               int kLen, float scale,
                                               const float* __restrict__ bias,
                                               float* __restrict__ Cf,
                                               u16* __restrict__ Cb, int ldC,
                                               float* __restrict__ Cpart, int Mtot,
                                               int swz) {
    __shared__ u16 As[2][128 * 32];
    __shared__ u16 Bs[2][128 * 32];
    const int tid = threadIdx.x;
    const int wave = tid >> 6, lane = tid & 63;
    const int wm = wave >> 1, wn = wave & 1;
    int nT, mT, z;
    if (swz == 1) {
        int L = blockIdx.x;
        z = L & 7; int r = L >> 3;
        nT = r >> 4; mT = r & 15;
    } else if (swz == 2) {
        int L = blockIdx.x;
        int c = L & 7, r = L >> 3;
        nT = (r % 11) * 8 + c; mT = r / 11; z = 0;
    } else {
        nT = blockIdx.x; mT = blockIdx.y; z = blockIdx.z;
    }
    const int m0 = mT * 128, n0 = nT * 128;
    const size_t kOff = (size_t)z * kLen;

    const int chl = (((lane & 3) ^ ((lane >> 3) & 3))) * 8;
    const u16* aG = A + (size_t)(m0 + wave * 32 + (lane >> 2)) * ldA + kOff + chl;
    const u16* bG = B + (size_t)(n0 + wave * 32 + (lane >> 2)) * ldB + kOff + chl;
    const size_t aS = (size_t)16 * ldA;
    const size_t bS = (size_t)16 * ldB;
    u16* aL0 = &As[0][(wave * 32) * 32];
    u16* aL1 = &As[0][(wave * 32 + 16) * 32];
    u16* aH0 = &As[1][(wave * 32) * 32];
    u16* aH1 = &As[1][(wave * 32 + 16) * 32];
    u16* bL0 = &Bs[0][(wave * 32) * 32];
    u16* bL1 = &Bs[0][(wave * 32 + 16) * 32];
    u16* bH0 = &Bs[1][(wave * 32) * 32];
    u16* bH1 = &Bs[1][(wave * 32 + 16) * 32];

    f32x4 acc[4][4];
#pragma unroll
    for (int i = 0; i < 4; i++)
#pragma unroll
        for (int j = 0; j < 4; j++) acc[i][j] = (f32x4){0.f, 0.f, 0.f, 0.f};

    const int ml = lane & 15, kq8 = lane >> 4;
    const int kqs = (kq8 ^ ((ml >> 1) & 3)) * 8;
    const u16* aRd0 = &As[0][(wm * 64 + ml) * 32 + kqs];
    const u16* bRd0 = &Bs[0][(wn * 64 + ml) * 32 + kqs];
    const u16* aRd1 = &As[1][(wm * 64 + ml) * 32 + kqs];
    const u16* bRd1 = &Bs[1][(wn * 64 + ml) * 32 + kqs];

    for (int k = 0; k < kLen; k += 64) {
        GLOAD_LDS16(aG, aL0);
        GLOAD_LDS16(aG + aS, aL1);
        GLOAD_LDS16(aG + 32, aH0);
        GLOAD_LDS16(aG + aS + 32, aH1);
        GLOAD_LDS16(bG, bL0);
        GLOAD_LDS16(bG + bS, bL1);
        GLOAD_LDS16(bG + 32, bH0);
        GLOAD_LDS16(bG + bS + 32, bH1);
        aG += 64; bG += 64;
        __syncthreads();
        {
            bf16x8 af[4], bfv[4];
#pragma unroll
            for (int i = 0; i < 4; i++) af[i]  = *(const bf16x8*)(aRd0 + i * 16 * 32);
#pragma unroll
            for (int j = 0; j < 4; j++) bfv[j] = *(const bf16x8*)(bRd0 + j * 16 * 32);
#pragma unroll
            for (int i = 0; i < 4; i++)
#pragma unroll
                for (int j = 0; j < 4; j++)
                    acc[i][j] = __builtin_amdgcn_mfma_f32_16x16x32_bf16(af[i], bfv[j], acc[i][j], 0, 0, 0);
        }
        {
            bf16x8 af[4], bfv[4];
#pragma unroll
            for (int i = 0; i < 4; i++) af[i]  = *(const bf16x8*)(aRd1 + i * 16 * 32);
#pragma unroll
            for (int j = 0; j < 4; j++) bfv[j] = *(const bf16x8*)(bRd1 + j * 16 * 32);
#pragma unroll
            for (int i = 0; i < 4; i++)
#pragma unroll
                for (int j = 0; j < 4; j++)
                    acc[i][j] = __builtin_amdgcn_mfma_f32_16x16x32_bf16(af[i], bfv[j], acc[i][j], 0, 0, 0);
        }
        __syncthreads();
    }

    const int q = lane >> 4, nl = lane & 15;
    if (Cpart) {
        float* outP = Cpart + (size_t)z * Mtot * ldC;
#pragma unroll
        for (int i = 0; i < 4; i++)
#pragma unroll
            for (int j = 0; j < 4; j++)
#pragma unroll
                for (int reg = 0; reg < 4; reg++) {
                    int row = m0 + wm * 64 + i * 16 + q * 4 + reg;
                    int col = n0 + wn * 64 + j * 16 + nl;
                    outP[(size_t)row * ldC + col] = acc[i][j][reg];
                }
    } else {
#pragma unroll
        for (int i = 0; i < 4; i++)
#pragma unroll
            for (int j = 0; j < 4; j++)
#pragma unroll
                for (int reg = 0; reg < 4; reg++) {
                    int row = m0 + wm * 64 + i * 16 + q * 4 + reg;
                    int col = n0 + wn * 64 + j * 16 + nl;
                    float v = acc[i][j][reg] * scale + (bias ? bias[col] : 0.0f);
                    if (Cf) Cf[(size_t)row * ldC + col] = v;
                    else    Cb[(size_t)row * ldC + col] = f2bf(v);
                }
    }
}

// ---------------------------------------------------------------- GEMM 256-tile, 8-wave, single-barrier tile
// Per K-64 tile t (buf p = t&1):
//   1. issue ALL 8 staging loads for tile t+1 into buf p^1   (issue-early: the
//      boundary vmcnt(0) then has a full tile (~1500+ cy) of distance -> ~free)
//   2. ds_read A-lo (f0..3, both kh) + B (g0..3, both kh) as plain vector
//      loads; MFMA quadrants Q0,Q1; ds_read A-hi (reuse regs); Q2,Q3.
//      Compiler inserts counted lgkmcnt waits -> read-drain overlaps MFMA
//      (m97-verified behavior), no phase lockstep, no intra-tile barriers.
//   3. vmcnt(0) + s_barrier at tile end only.
// Correctness: all tile-t reads touch buf p; staging writes buf p^1; the
// boundary drain+barrier orders buffer swap. LDS chunk-XOR swizzle as k_gemm2.
#define VMCNT0 asm volatile("s_waitcnt vmcnt(0)" ::: "memory")
#define BARX() __builtin_amdgcn_s_barrier()

#define STG_A(p, kh, rh, kb) GLOAD_LDS16(aB + (size_t)(rh) * aH + (kb) + (kh) * 32, \
                                         &As[p][kh][((rh) * 128 + wave * 16) * 32])
#define STG_B(p, kh, rh, kb) GLOAD_LDS16(bB + (size_t)(rh) * bH + (kb) + (kh) * 32, \
                                         &Bs[p][kh][((rh) * 128 + wave * 16) * 32])
// quadrant MFMA: rows fb..fb+3 from a[], cols gb..gb+1 from b[] (kh-paired)
#define MMQ2(fb, gb) do { _Pragma("unroll") \
    for (int ff = 0; ff < 4; ff++) { _Pragma("unroll") \
        for (int gg = 0; gg < 2; gg++) { \
            acc[(fb)+ff][(gb)+gg] = __builtin_amdgcn_mfma_f32_16x16x32_bf16(a[2*ff],   b[2*((gb)+gg)],   acc[(fb)+ff][(gb)+gg], 0, 0, 0); \
            acc[(fb)+ff][(gb)+gg] = __builtin_amdgcn_mfma_f32_16x16x32_bf16(a[2*ff+1], b[2*((gb)+gg)+1], acc[(fb)+ff][(gb)+gg], 0, 0, 0); } } } while (0)

__global__ __launch_bounds__(512, 2) void k_gemm256(const u16* __restrict__ A, int ldA,
                                                    const u16* __restrict__ B, int ldB,
                                                    int kLen, float scale,
                                                    const float* __restrict__ bias,
                                                    u16* __restrict__ Cb, int ldC,
                                                    float* __restrict__ Cpart, int Mtot,
                                                    int swz) {
    __shared__ __align__(16) u16 As[2][2][256 * 32];   // [buf][kh][row*32+k]  64 KB
    __shared__ __align__(16) u16 Bs[2][2][256 * 32];   // 64 KB
    const int tid = threadIdx.x;
    const int lane = tid & 63, wave = tid >> 6;
    const int wm = wave >> 2, wn = wave & 3;
    int mT, nT, z;
    if (swz == 1) {
        // GEMM1: 256 blocks. XCD = z = L&7 (one K-slice per XCD). Within XCD:
        // nT fastest (B working set L2-resident), A-panel read once.
        z = blockIdx.x & 7; int r = blockIdx.x >> 3; nT = r & 3; mT = r >> 2;
    } else {
        // GEMM2: 352 blocks. x = XCD; mT fastest within fixed nT (B-panel
        // reused 8x consecutively from L2). Tail nT=40..43 split across x.
        int x = blockIdx.x & 7, j = blockIdx.x >> 3;
        int nti = j >> 3; mT = j & 7;
        if (nti < 5)      nT = nti * 8 + x;
        else if (x < 4)   nT = 40 + x;              // mT = j&7 in 0..3
        else            { nT = 40 + (x - 4); mT = (j & 7) + 4; }
        z = 0;
    }
    const int m0 = mT * 256, n0 = nT * 256;
    const size_t kOff = (size_t)z * kLen;
    const int nTi = kLen >> 6;          // K-64 tiles, >= 2

    const int chl = ((tid & 3) ^ ((tid >> 3) & 3)) * 8;
    const u16* aB = A + (size_t)(m0 + (tid >> 2)) * ldA + kOff + chl;
    const u16* bB = B + (size_t)(n0 + (tid >> 2)) * ldB + kOff + chl;
    const size_t aH = (size_t)128 * ldA;
    const size_t bH = (size_t)128 * ldB;

    const int ml = lane & 15, kq8 = lane >> 4;
    const int kqs = (kq8 ^ ((ml >> 1) & 3)) * 8;
    const int aro = (wm * 128 + ml) * 32 + kqs;
    const int bro = (wn * 64 + ml) * 32 + kqs;

    f32x4 acc[8][4];
#pragma unroll
    for (int f = 0; f < 8; f++)
#pragma unroll
        for (int g = 0; g < 4; g++) acc[f][g] = (f32x4){0.f, 0.f, 0.f, 0.f};
    bf16x8 a[8], b[8];

    // prologue: stage tile 0 fully, drain, barrier
    STG_A(0, 0, 0, 0); STG_A(0, 0, 1, 0); STG_A(0, 1, 0, 0); STG_A(0, 1, 1, 0);
    STG_B(0, 0, 0, 0); STG_B(0, 0, 1, 0); STG_B(0, 1, 0, 0); STG_B(0, 1, 1, 0);
    VMCNT0;
    BARX();

    for (int t = 0; t < nTi; t++) {
        const int p = t & 1, p1 = p ^ 1;
        const int kb1 = (t + 1) << 6;
        const bool s1 = (t + 1) < nTi;
        // 1. issue-early: full staging of tile t+1
        if (s1) {
            STG_A(p1, 0, 0, kb1); STG_A(p1, 0, 1, kb1);
            STG_A(p1, 1, 0, kb1); STG_A(p1, 1, 1, kb1);
            STG_B(p1, 0, 0, kb1); STG_B(p1, 0, 1, kb1);
            STG_B(p1, 1, 0, kb1); STG_B(p1, 1, 1, kb1);
        }
        // 2. fragments + MFMA, compiler-scheduled (counted lgkm waits)
#pragma unroll
        for (int f = 0; f < 4; f++) {
            a[2*f]   = *(const bf16x8*)&As[p][0][aro + f * 512];
            a[2*f+1] = *(const bf16x8*)&As[p][1][aro + f * 512];
        }
#pragma unroll
        for (int g = 0; g < 4; g++) {
            b[2*g]   = *(const bf16x8*)&Bs[p][0][bro + g * 512];
            b[2*g+1] = *(const bf16x8*)&Bs[p][1][bro + g * 512];
        }
        MMQ2(0, 0);            // f0..3 x g0..1
        MMQ2(0, 2);            // f0..3 x g2..3
#pragma unroll
        for (int f = 0; f < 4; f++) {
            a[2*f]   = *(const bf16x8*)&As[p][0][aro + (f + 4) * 512];
            a[2*f+1] = *(const bf16x8*)&As[p][1][aro + (f + 4) * 512];
        }
        MMQ2(4, 0);            // f4..7 x g0..1
        MMQ2(4, 2);            // f4..7 x g2..3
        // 3. boundary: staged loads landed long ago; swap buffers
        if (s1) VMCNT0;
        BARX();
    }

    const int q = lane >> 4, nl = lane & 15;
    if (Cpart) {
        float* outP = Cpart + (size_t)z * Mtot * ldC;
#pragma unroll
        for (int f = 0; f < 8; f++)
#pragma unroll
            for (int g = 0; g < 4; g++)
#pragma unroll
                for (int reg = 0; reg < 4; reg++) {
                    int row = m0 + wm * 128 + f * 16 + q * 4 + reg;
                    int col = n0 + wn * 64 + g * 16 + nl;
                    outP[(size_t)row * ldC + col] = acc[f][g][reg];
                }
    } else {
#pragma unroll
        for (int f = 0; f < 8; f++)
#pragma unroll
            for (int g = 0; g < 4; g++)
#pragma unroll
                for (int reg = 0; reg < 4; reg++) {
                    int row = m0 + wm * 128 + f * 16 + q * 4 + reg;
                    int col = n0 + wn * 64 + g * 16 + nl;
                    float v = acc[f][g][reg] * scale + (bias ? bias[col] : 0.0f);
                    Cb[(size_t)row * ldC + col] = f2bf(v);
                }
    }
}

// sum split-K partials + epilogue
__global__ __launch_bounds__(256) void k_reduce(const float* __restrict__ part, size_t stride,
                                                int SK, int total, int N, float scale,
                                                const float* __restrict__ bias,
                                                float* __restrict__ outF, u16* __restrict__ outB) {
    int i = blockIdx.x * 256 + threadIdx.x;
    if (i >= total) return;
    float s = 0.f;
    for (int z = 0; z < SK; z++) s += part[(size_t)z * stride + i];
    float v = s * scale + (bias ? bias[i % N] : 0.0f);
    if (outF) outF[i] = v;
    else      outB[i] = f2bf(v);
}

// ---------------------------------------------------------------- rowwise LN
__device__ __forceinline__ float blockReduce(float v, float* red) {
#pragma unroll
    for (int off = 32; off > 0; off >>= 1) v += __shfl_down(v, off);
    __syncthreads();
    if ((threadIdx.x & 63) == 0) red[threadIdx.x >> 6] = v;
    __syncthreads();
    return red[0] + red[1] + red[2] + red[3];
}

__global__ __launch_bounds__(256) void k_ln_fwd(const float* __restrict__ X, int D,
    const float* __restrict__ g, const float* __restrict__ be,
    float* __restrict__ mu_out, float* __restrict__ r_out,
    u16* __restrict__ a_bf, float* __restrict__ a_f32) {
    __shared__ float red[4];
    int b = blockIdx.x, tid = threadIdx.x;
    const float* x = X + (size_t)b * D;
    int nd = D >> 8;
    float s = 0.f, s2 = 0.f;
    for (int r = 0; r < nd; r++) { float v = x[tid + (r << 8)]; s += v; s2 += v * v; }
    s = blockReduce(s, red);
    s2 = blockReduce(s2, red);
    float mu = s / D;
    float var = s2 / D - mu * mu;
    float rst = rsqrtf(var + 1e-6f);
    if (tid == 0) { mu_out[b] = mu; r_out[b] = rst; }
    for (int r = 0; r < nd; r++) {
        int i = tid + (r << 8);
        float xh = (x[i] - mu) * rst;
        float ln = xh * g[i] + be[i];
        float a = ln / (1.0f + expf(-ln));
        if (a_bf)  a_bf[(size_t)b * D + i] = f2bf(a);
        if (a_f32) a_f32[(size_t)b * D + i] = a;
    }
}

__global__ __launch_bounds__(256) void k_ln_bwd(const float* __restrict__ dup,
    const float* __restrict__ X, const float* __restrict__ mu_in, const float* __restrict__ r_in,
    const float* __restrict__ g, const float* __restrict__ be,
    u16* __restrict__ out_bf, int D) {
    __shared__ float red[4];
    int b = blockIdx.x, tid = threadIdx.x;
    const float* x = X + (size_t)b * D;
    float mu = mu_in[b], rst = r_in[b];
    int nd = D >> 8;
    float w_[4], xh_[4];
    float sw = 0.f, swx = 0.f;
    for (int r = 0; r < nd; r++) {
        int i = tid + (r << 8);
        float xh = (x[i] - mu) * rst;
        float ln = xh * g[i] + be[i];
        float sg = 1.0f / (1.0f + expf(-ln));
        float dsilu = sg * (1.0f + ln * (1.0f - sg));
        float d = dup ? dup[(size_t)b * D + i] : 1.0f;
        float w = g[i] * dsilu * d;
        w_[r] = w; xh_[r] = xh;
        sw += w; swx += w * xh;
    }
    sw = blockReduce(sw, red);
    swx = blockReduce(swx, red);
    float invD = 1.0f / D;
    for (int r = 0; r < nd; r++) {
        int i = tid + (r << 8);
        float dx = rst * (w_[r] - sw * invD - xh_[r] * swx * invD);
        out_bf[(size_t)b * D + i] = f2bf(dx);
    }
}

// ---------------------------------------------------------------- packed contraction
__global__ __launch_bounds__(256) void k_contract_p(const u16* __restrict__ Gp,
                                                    const float* __restrict__ t,
                                                    float* __restrict__ y) {
    __shared__ u16 gp_s[NPACK];
    __shared__ float xs[480];
    int b = blockIdx.x, tid = threadIdx.x;
    const uint4* gsrc = (const uint4*)(Gp + (size_t)b * NPACK);
    for (int j = tid; j < NPACK / 8; j += 256) ((uint4*)gp_s)[j] = gsrc[j];
    for (int j = tid; j < 480; j += 256) xs[j] = t[(size_t)b * 480 + j];
    __syncthreads();
    int wave = tid >> 6, lane = tid & 63;
    float* yr = y + (size_t)b * 480;
    for (int r = 0; r < 32; r++) {
        int u = wave * 32 + r;
        int v0 = lane, v1 = lane + 64;
        float s = bf2f(gp_s[pk0(u, v0)]) * xs[v0] + bf2f(gp_s[pk0(u, v1)]) * xs[v1];
#pragma unroll
        for (int off = 32; off > 0; off >>= 1) s += __shfl_down(s, off);
        if (lane == 0) yr[u] = s;
    }
    for (int r = 0; r < 16; r++) {
        int u = wave * 16 + r;
        float gv = bf2f(gp_s[pk1(u, lane)]);
        float a0 = gv * xs[128 + lane * 3 + 0];
        float a1 = gv * xs[128 + lane * 3 + 1];
        float a2 = gv * xs[128 + lane * 3 + 2];
#pragma unroll
        for (int off = 32; off > 0; off >>= 1) {
            a0 += __shfl_down(a0, off);
            a1 += __shfl_down(a1, off);
            a2 += __shfl_down(a2, off);
        }
        if (lane == 0) {
            yr[128 + u * 3 + 0] = a0;
            yr[128 + u * 3 + 1] = a1;
            yr[128 + u * 3 + 2] = a2;
        }
    }
    for (int r = 0; r < 8; r++) {
        int u = wave * 8 + r;
        bool act = lane < 32;
        float gv = act ? bf2f(gp_s[pk2(u, act ? lane : 0)]) : 0.f;
        float a[5];
#pragma unroll
        for (int m = 0; m < 5; m++)
            a[m] = act ? gv * xs[320 + lane * 5 + m] : 0.f;
#pragma unroll
        for (int off = 32; off > 0; off >>= 1)
#pragma unroll
            for (int m = 0; m < 5; m++) a[m] += __shfl_down(a[m], off);
        if (lane == 0)
#pragma unroll
            for (int m = 0; m < 5; m++) yr[320 + u * 5 + m] = a[m];
    }
}

// ---------------------------------------------------------------- launch
extern "C" void kernel_launch(void* const* d_in, const int* in_sizes, int n_in,
                              void* d_out, int out_size, void* d_ws, size_t ws_size,
                              hipStream_t stream) {
    const float* t   = (const float*)d_in[0];
    const float* w0  = (const float*)d_in[1];
    const float* w1  = (const float*)d_in[2];
    const float* w2  = (const float*)d_in[3];
    const float* W1  = (const float*)d_in[4];
    const float* b1  = (const float*)d_in[5];
    const float* g1  = (const float*)d_in[6];
    const float* be1 = (const float*)d_in[7];
    const float* W2  = (const float*)d_in[8];
    const float* b2  = (const float*)d_in[9];
    const float* g2  = (const float*)d_in[10];
    const float* be2 = (const float*)d_in[11];

    float* xout = (float*)d_out;                    // 2048*256
    float* yout = xout + (size_t)2048 * 256;        // 2048*480

    char* ws = (char*)d_ws;
    size_t off = 0;
    auto alloc = [&](size_t bytes) -> void* {
        void* p = ws + off;
        off += (bytes + 255) & ~(size_t)255;
        return p;
    };
    u16*   PG    = (u16*)alloc((size_t)2048 * NPACK * 2);   // Ppack, later Gp (aliased)
    u16*   Wsym  = (u16*)alloc((size_t)NPACK * 1024 * 2);   // packed Wsym [i,h]
    u16*   Wt    = (u16*)alloc((size_t)1024 * NPACK * 2);   // packed Wsym^T [h,i]
    u16*   uvtab = (u16*)alloc((size_t)NPACK * 2);
    u16*   W1b   = (u16*)alloc((size_t)1024 * 1024 * 2);
    u16*   W1tb  = (u16*)alloc((size_t)1024 * 1024 * 2);
    u16*   W2b   = (u16*)alloc((size_t)1024 * 256 * 2);
    u16*   W2tb  = (u16*)alloc((size_t)256 * 1024 * 2);
    u16*   h_bf  = (u16*)alloc((size_t)2048 * 1024 * 2);
    float* h1pre = (float*)alloc((size_t)2048 * 1024 * 4);
    float* mu1   = (float*)alloc(2048 * 4);
    float* r1    = (float*)alloc(2048 * 4);
    u16*   a1_bf = (u16*)alloc((size_t)2048 * 1024 * 2);
    float* h2pre = (float*)alloc((size_t)2048 * 256 * 4);
    float* mu2   = (float*)alloc(2048 * 4);
    float* r2    = (float*)alloc(2048 * 4);
    u16*   dh2b  = (u16*)alloc((size_t)2048 * 256 * 2);
    float* d_a1  = (float*)alloc((size_t)2048 * 1024 * 4);
    u16*   dh1b  = (u16*)alloc((size_t)2048 * 1024 * 2);
    u16*   de_bf = (u16*)alloc((size_t)2048 * 1024 * 2);
    float* Cpart = (float*)(ws + off);
    size_t cpartBytes = (ws_size > off) ? (ws_size - off) : 0;
    (void)in_sizes; (void)n_in; (void)out_size;

    const float sF = 1.0f / sqrtf(21504.0f);

    // generic GEMM helper (MLP GEMMs): 3-D grid, optional split-K
    auto gemm = [&](const u16* A, int ldA, const u16* B, int ldB, int M, int N, int K,
                    int SKwant, float scale, const float* bias,
                    float* Cf, u16* Cb, int ldC) {
        int SK = SKwant;
        size_t slice = (size_t)M * ldC * 4;
        if (SK > 1 && cpartBytes < 2 * slice) SK = 1;
        if (SK > 1 && (size_t)SK * slice > cpartBytes) SK = (int)(cpartBytes / slice);
        while (SK > 1 && !((K % SK) == 0 && ((K / SK) % 64) == 0)) SK--;
        dim3 grid(N / 128, M / 128, SK);
        if (SK > 1) {
            k_gemm2<<<grid, 256, 0, stream>>>(A, ldA, B, ldB, K / SK, 0.f, nullptr,
                                              nullptr, nullptr, ldC, Cpart, M, 0);
            int total = M * ldC;
            k_reduce<<<(total + 255) / 256, 256, 0, stream>>>(Cpart, (size_t)M * ldC, SK,
                                                              total, N, scale, bias, Cf, Cb);
        } else {
            k_gemm2<<<grid, 256, 0, stream>>>(A, ldA, B, ldB, K, scale, bias,
                                              Cf, Cb, ldC, nullptr, M, 0);
        }
    };

    // index table + packed weights
    k_uvall<<<(21504 + NPACK - NVALID + 255) / 256, 256, 0, stream>>>(uvtab);
    k_packw<<<dim3(NPACK / 32, 4), 256, 0, stream>>>(w0, w1, w2, uvtab, Wsym, Wt);

    // small MLP weights
    k_transpose<<<dim3(32, 32), 256, 0, stream>>>(W1, 1024, 1024, W1tb, 1024);
    k_transpose<<<dim3(8, 32), 256, 0, stream>>>(W2, 1024, 256, W2tb, 1024);
    k_convert<<<1024 * 1024 / 1024, 256, 0, stream>>>(W1, W1b, 1024 * 1024 / 4);
    k_convert<<<1024 * 256 / 1024, 256, 0, stream>>>(W2, W2b, 1024 * 256 / 4);

    // packed features
    k_features_pack<<<2048, 256, 0, stream>>>(t, uvtab, PG);

    // GEMM1: h = sF * Ppack @ Wt^T. 256-tile: 8z x (4nT x 8mT) = 256 blocks, kLen=1408.
    k_gemm256<<<dim3(256), 512, 0, stream>>>(PG, NPACK, Wt, NPACK, NPACK / 8, 0.f, nullptr,
                                             nullptr, 1024, Cpart, 2048, 1);
    {
        int total = 2048 * 1024;
        k_reduce<<<(total + 255) / 256, 256, 0, stream>>>(Cpart, (size_t)2048 * 1024, 8,
                                                          total, 1024, sF, nullptr,
                                                          nullptr, h_bf);
    }

    // MLP forward
    gemm(h_bf, 1024, W1tb, 1024, 2048, 1024, 1024, 4, 1.0f, b1, h1pre, nullptr, 1024);
    k_ln_fwd<<<2048, 256, 0, stream>>>(h1pre, 1024, g1, be1, mu1, r1, a1_bf, nullptr);
    gemm(a1_bf, 1024, W2tb, 1024, 2048, 256, 1024, 8, 1.0f, b2, h2pre, nullptr, 256);
    k_ln_fwd<<<2048, 256, 0, stream>>>(h2pre, 256, g2, be2, mu2, r2, nullptr, xout);

    // backward
    k_ln_bwd<<<2048, 256, 0, stream>>>(nullptr, h2pre, mu2, r2, g2, be2, dh2b, 256);
    gemm(dh2b, 256, W2b, 256, 2048, 1024, 256, 4, 1.0f, nullptr, d_a1, nullptr, 1024);
    k_ln_bwd<<<2048, 256, 0, stream>>>(d_a1, h1pre, mu1, r1, g1, be1, dh1b, 1024);
    gemm(dh1b, 1024, W1b, 1024, 2048, 1024, 1024, 4, sF, nullptr, nullptr, de_bf, 1024);

    // GEMM2: Gp = de @ Wsym^T. 256-tile: 352 blocks, K=1024, XCD-local B reuse.
    u16* Gp = PG;   // Ppack dead after GEMM1
    k_gemm256<<<dim3(352), 512, 0, stream>>>(de_bf, 1024, Wsym, 1024, 1024, 1.0f, nullptr,
                                             Gp, NPACK, nullptr, 2048, 2);

    // y from packed symmetric Gp (shuffle-reduce, no atomics)
    k_contract_p<<<2048, 256, 0, stream>>>(Gp, t, yout);
}

// Round 5
// 530.682 us; speedup vs baseline: 1.0190x; 1.0190x over previous
//
#include <hip/hip_runtime.h>
#include <math.h>

typedef unsigned short u16;
typedef __bf16 bf16x8 __attribute__((ext_vector_type(8)));
typedef float f32x4 __attribute__((ext_vector_type(4)));

#define NPACK  11264   // padded packed-pair count (88*128)
#define NVALID 10864   // 8256 + 2080 + 528
#define BASE1  8256
#define BASE2  10336

__device__ __forceinline__ u16 f2bf(float f) {
    unsigned u = __builtin_bit_cast(unsigned, f);
    u += 0x7FFFu + ((u >> 16) & 1u);
    return (u16)(u >> 16);
}
__device__ __forceinline__ float bf2f(u16 h) {
    return __builtin_bit_cast(float, ((unsigned)h) << 16);
}

#define GLOAD_LDS16(g, l)                                                     \
    __builtin_amdgcn_global_load_lds(                                         \
        (const __attribute__((address_space(1))) void*)(g),                   \
        (__attribute__((address_space(3))) void*)(l), 16, 0, 0)

// packed triangular index (u<=v), per segment
__device__ __forceinline__ int pk0(int a, int b) {
    int u = min(a, b), v = max(a, b);
    return u * 128 - (u * (u - 1)) / 2 + (v - u);
}
__device__ __forceinline__ int pk1(int a, int b) {
    int u = min(a, b), v = max(a, b);
    return BASE1 + u * 64 - (u * (u - 1)) / 2 + (v - u);
}
__device__ __forceinline__ int pk2(int a, int b) {
    int u = min(a, b), v = max(a, b);
    return BASE2 + u * 32 - (u * (u - 1)) / 2 + (v - u);
}

// ---------------------------------------------------------------- uv table (one launch)
__global__ __launch_bounds__(256) void k_uvall(u16* __restrict__ tab) {
    int j = blockIdx.x * 256 + threadIdx.x;
    if (j < 16384) {
        int u = j >> 7, v = j & 127;
        if (v >= u) tab[pk0(u, v)] = (u16)((u << 7) | v);
    } else if (j < 20480) {
        int k = j - 16384, u = k >> 6, v = k & 63;
        if (v >= u) tab[pk1(u, v)] = (u16)((1 << 14) | (u << 7) | v);
    } else if (j < 21504) {
        int k = j - 20480, u = k >> 5, v = k & 31;
        if (v >= u) tab[pk2(u, v)] = (u16)((2 << 14) | (u << 7) | v);
    } else {
        int k = j - 21504;
        if (NVALID + k < NPACK) tab[NVALID + k] = 0xFFFFu;
    }
}

// ---------------------------------------------------------------- packed weights
__global__ __launch_bounds__(256) void k_packw(const float* __restrict__ w0,
                                               const float* __restrict__ w1,
                                               const float* __restrict__ w2,
                                               const u16* __restrict__ tab,
                                               u16* __restrict__ Wsym,
                                               u16* __restrict__ Wt) {
    __shared__ u16 tile[32][258];
    __shared__ u16 te[32];
    int i0 = blockIdx.x * 32, h0 = blockIdx.y * 256, tid = threadIdx.x;
    if (tid < 32) te[tid] = tab[i0 + tid];
    __syncthreads();
    const float s1 = 0.57735026918962576f, s2 = 0.44721359549995794f;
    for (int il = 0; il < 32; il++) {
        unsigned e = te[il];
        float val = 0.f;
        if ((e >> 14) != 3) {
            int seg = e >> 14, u = (e >> 7) & 127, v = e & 127;
            const float* wb; int S; float sc;
            if (seg == 0)      { wb = w0; S = 128; sc = 1.f; }
            else if (seg == 1) { wb = w1; S = 64;  sc = s1; }
            else               { wb = w2; S = 32;  sc = s2; }
            val = sc * (wb[(size_t)(u * S + v) * 1024 + h0 + tid] +
                        wb[(size_t)(v * S + u) * 1024 + h0 + tid]);
        }
        u16 bv = f2bf(val);
        Wsym[(size_t)(i0 + il) * 1024 + h0 + tid] = bv;
        tile[il][tid] = bv;
    }
    __syncthreads();
    union { u16 a[32]; uint4 q[4]; } pk;
#pragma unroll
    for (int il = 0; il < 32; il++) pk.a[il] = tile[il][tid];
    uint4* dst = (uint4*)(Wt + (size_t)(h0 + tid) * NPACK + i0);
#pragma unroll
    for (int q = 0; q < 4; q++) dst[q] = pk.q[q];
}

// ---------------------------------------------------------------- converts
__global__ __launch_bounds__(256) void k_convert(const float* __restrict__ in,
                                                 u16* __restrict__ out, int n4) {
    int i = blockIdx.x * 256 + threadIdx.x;
    if (i >= n4) return;
    float4 v = ((const float4*)in)[i];
    union { u16 a[4]; unsigned long long q; } o;
    o.a[0] = f2bf(v.x); o.a[1] = f2bf(v.y); o.a[2] = f2bf(v.z); o.a[3] = f2bf(v.w);
    ((unsigned long long*)out)[i] = o.q;
}

__global__ __launch_bounds__(256) void k_transpose(const float* __restrict__ in, int R, int C,
                                                   u16* __restrict__ out, int ldOut) {
    __shared__ float tile[32][33];
    int tr0 = blockIdx.y * 32;
    int tc0 = blockIdx.x * 32;
    int lr = threadIdx.x >> 5;
    int lc = threadIdx.x & 31;
#pragma unroll
    for (int i = 0; i < 4; i++) {
        int rr = lr + i * 8;
        tile[rr][lc] = in[(size_t)(tr0 + rr) * C + tc0 + lc];
    }
    __syncthreads();
#pragma unroll
    for (int i = 0; i < 4; i++) {
        int rr = lr + i * 8;
        out[(size_t)(tc0 + rr) * ldOut + tr0 + lc] = f2bf(tile[lc][rr]);
    }
}

// ---------------------------------------------------------------- packed features
__global__ __launch_bounds__(256) void k_features_pack(const float* __restrict__ t,
                                                       const u16* __restrict__ tab,
                                                       u16* __restrict__ P) {
    __shared__ u16 tab_s[NPACK];
    __shared__ float tr[480];
    int b = blockIdx.x, tid = threadIdx.x;
    for (int j = tid; j < NPACK / 8; j += 256)
        ((uint4*)tab_s)[j] = ((const uint4*)tab)[j];
    for (int j = tid; j < 480; j += 256) tr[j] = t[(size_t)b * 480 + j];
    __syncthreads();
    u16* row = P + (size_t)b * NPACK;
    for (int i = tid; i < NPACK; i += 256) {
        unsigned e = tab_s[i];
        float p = 0.f;
        if ((e >> 14) != 3) {
            int seg = e >> 14, u = (e >> 7) & 127, v = e & 127;
            if (seg == 0) p = tr[u] * tr[v];
            else if (seg == 1) {
                const float* x1 = tr + 128;
                p = x1[u*3]*x1[v*3] + x1[u*3+1]*x1[v*3+1] + x1[u*3+2]*x1[v*3+2];
            } else {
                const float* x2 = tr + 320;
#pragma unroll
                for (int m = 0; m < 5; m++) p += x2[u*5+m] * x2[v*5+m];
            }
            if (u == v) p *= 0.5f;
        }
        row[i] = f2bf(p);
    }
}

// ---------------------------------------------------------------- GEMM 128-tile (round-0, MLP sizes)
__global__ __launch_bounds__(256) void k_gemm2(const u16* __restrict__ A, int ldA,
                                               const u16* __restrict__ B, int ldB,
                                               int kLen, float scale,
                                               const float* __restrict__ bias,
                                               float* __restrict__ Cf,
                                               u16* __restrict__ Cb, int ldC,
                                               float* __restrict__ Cpart, int Mtot,
                                               int swz) {
    __shared__ u16 As[2][128 * 32];
    __shared__ u16 Bs[2][128 * 32];
    const int tid = threadIdx.x;
    const int wave = tid >> 6, lane = tid & 63;
    const int wm = wave >> 1, wn = wave & 1;
    int nT, mT, z;
    if (swz == 1) {
        int L = blockIdx.x;
        z = L & 7; int r = L >> 3;
        nT = r >> 4; mT = r & 15;
    } else if (swz == 2) {
        int L = blockIdx.x;
        int c = L & 7, r = L >> 3;
        nT = (r % 11) * 8 + c; mT = r / 11; z = 0;
    } else {
        nT = blockIdx.x; mT = blockIdx.y; z = blockIdx.z;
    }
    const int m0 = mT * 128, n0 = nT * 128;
    const size_t kOff = (size_t)z * kLen;

    const int chl = (((lane & 3) ^ ((lane >> 3) & 3))) * 8;
    const u16* aG = A + (size_t)(m0 + wave * 32 + (lane >> 2)) * ldA + kOff + chl;
    const u16* bG = B + (size_t)(n0 + wave * 32 + (lane >> 2)) * ldB + kOff + chl;
    const size_t aS = (size_t)16 * ldA;
    const size_t bS = (size_t)16 * ldB;
    u16* aL0 = &As[0][(wave * 32) * 32];
    u16* aL1 = &As[0][(wave * 32 + 16) * 32];
    u16* aH0 = &As[1][(wave * 32) * 32];
    u16* aH1 = &As[1][(wave * 32 + 16) * 32];
    u16* bL0 = &Bs[0][(wave * 32) * 32];
    u16* bL1 = &Bs[0][(wave * 32 + 16) * 32];
    u16* bH0 = &Bs[1][(wave * 32) * 32];
    u16* bH1 = &Bs[1][(wave * 32 + 16) * 32];

    f32x4 acc[4][4];
#pragma unroll
    for (int i = 0; i < 4; i++)
#pragma unroll
        for (int j = 0; j < 4; j++) acc[i][j] = (f32x4){0.f, 0.f, 0.f, 0.f};

    const int ml = lane & 15, kq8 = lane >> 4;
    const int kqs = (kq8 ^ ((ml >> 1) & 3)) * 8;
    const u16* aRd0 = &As[0][(wm * 64 + ml) * 32 + kqs];
    const u16* bRd0 = &Bs[0][(wn * 64 + ml) * 32 + kqs];
    const u16* aRd1 = &As[1][(wm * 64 + ml) * 32 + kqs];
    const u16* bRd1 = &Bs[1][(wn * 64 + ml) * 32 + kqs];

    for (int k = 0; k < kLen; k += 64) {
        GLOAD_LDS16(aG, aL0);
        GLOAD_LDS16(aG + aS, aL1);
        GLOAD_LDS16(aG + 32, aH0);
        GLOAD_LDS16(aG + aS + 32, aH1);
        GLOAD_LDS16(bG, bL0);
        GLOAD_LDS16(bG + bS, bL1);
        GLOAD_LDS16(bG + 32, bH0);
        GLOAD_LDS16(bG + bS + 32, bH1);
        aG += 64; bG += 64;
        __syncthreads();
        {
            bf16x8 af[4], bfv[4];
#pragma unroll
            for (int i = 0; i < 4; i++) af[i]  = *(const bf16x8*)(aRd0 + i * 16 * 32);
#pragma unroll
            for (int j = 0; j < 4; j++) bfv[j] = *(const bf16x8*)(bRd0 + j * 16 * 32);
#pragma unroll
            for (int i = 0; i < 4; i++)
#pragma unroll
                for (int j = 0; j < 4; j++)
                    acc[i][j] = __builtin_amdgcn_mfma_f32_16x16x32_bf16(af[i], bfv[j], acc[i][j], 0, 0, 0);
        }
        {
            bf16x8 af[4], bfv[4];
#pragma unroll
            for (int i = 0; i < 4; i++) af[i]  = *(const bf16x8*)(aRd1 + i * 16 * 32);
#pragma unroll
            for (int j = 0; j < 4; j++) bfv[j] = *(const bf16x8*)(bRd1 + j * 16 * 32);
#pragma unroll
            for (int i = 0; i < 4; i++)
#pragma unroll
                for (int j = 0; j < 4; j++)
                    acc[i][j] = __builtin_amdgcn_mfma_f32_16x16x32_bf16(af[i], bfv[j], acc[i][j], 0, 0, 0);
        }
        __syncthreads();
    }

    const int q = lane >> 4, nl = lane & 15;
    if (Cpart) {
        float* outP = Cpart + (size_t)z * Mtot * ldC;
#pragma unroll
        for (int i = 0; i < 4; i++)
#pragma unroll
            for (int j = 0; j < 4; j++)
#pragma unroll
                for (int reg = 0; reg < 4; reg++) {
                    int row = m0 + wm * 64 + i * 16 + q * 4 + reg;
                    int col = n0 + wn * 64 + j * 16 + nl;
                    outP[(size_t)row * ldC + col] = acc[i][j][reg];
                }
    } else {
#pragma unroll
        for (int i = 0; i < 4; i++)
#pragma unroll
            for (int j = 0; j < 4; j++)
#pragma unroll
                for (int reg = 0; reg < 4; reg++) {
                    int row = m0 + wm * 64 + i * 16 + q * 4 + reg;
                    int col = n0 + wn * 64 + j * 16 + nl;
                    float v = acc[i][j][reg] * scale + (bias ? bias[col] : 0.0f);
                    if (Cf) Cf[(size_t)row * ldC + col] = v;
                    else    Cb[(size_t)row * ldC + col] = f2bf(v);
                }
    }
}

// ---------------------------------------------------------------- GEMM 256-tile, 8-wave, quadrant phases
// R3 base (best measured) with ONE change: all 8 staging loads of tile t+1
// issue in phases 0/1 (4+4) instead of 2/2/2/2, so the tile-boundary vmcnt(0)
// has >=2 phases (~1200-1800 cy) of cover and retires ~free (T4 intent).
//  ph0: rd a[8](f0..3) + b[4](g0..1); STG_A x4  -> MFMA f0..3 x g0..1
//  ph1: rd b2[4](g2..3);              STG_B x4  -> MFMA f0..3 x g2..3
//  ph2: rd a[8](f4..7)                          -> MFMA f4..7 x g0..1
//  ph3: (no reads, no stages)                   -> MFMA f4..7 x g2..3
//  vmcnt(0) + barrier at tile boundary only.
#define VMCNT0 asm volatile("s_waitcnt vmcnt(0)" ::: "memory")
#define BARX() __builtin_amdgcn_s_barrier()

#define STG_A(p, kh, rh, kb) GLOAD_LDS16(aB + (size_t)(rh) * aH + (kb) + (kh) * 32, \
                                         &As[p][kh][((rh) * 128 + wave * 16) * 32])
#define STG_B(p, kh, rh, kb) GLOAD_LDS16(bB + (size_t)(rh) * bH + (kb) + (kh) * 32, \
                                         &Bs[p][kh][((rh) * 128 + wave * 16) * 32])
// MFMA quadrant: rows fb..fb+3 (a regs), cols gb..gb+1 (bv regs), both kh
#define MMQ(fb, gb, bv) do { _Pragma("unroll") \
    for (int ff = 0; ff < 4; ff++) { _Pragma("unroll") \
        for (int gg = 0; gg < 2; gg++) { \
            acc[(fb)+ff][(gb)+gg] = __builtin_amdgcn_mfma_f32_16x16x32_bf16(a[2*ff],   bv[2*gg],   acc[(fb)+ff][(gb)+gg], 0, 0, 0); \
            acc[(fb)+ff][(gb)+gg] = __builtin_amdgcn_mfma_f32_16x16x32_bf16(a[2*ff+1], bv[2*gg+1], acc[(fb)+ff][(gb)+gg], 0, 0, 0); } } } while (0)

__global__ __launch_bounds__(512, 2) void k_gemm256(const u16* __restrict__ A, int ldA,
                                                    const u16* __restrict__ B, int ldB,
                                                    int kLen, float scale,
                                                    const float* __restrict__ bias,
                                                    u16* __restrict__ Cb, int ldC,
                                                    float* __restrict__ Cpart, int Mtot,
                                                    int swz) {
    __shared__ __align__(16) u16 As[2][2][256 * 32];   // [buf][kh][row*32+k]  64 KB
    __shared__ __align__(16) u16 Bs[2][2][256 * 32];   // 64 KB
    const int tid = threadIdx.x;
    const int lane = tid & 63, wave = tid >> 6;
    const int wm = wave >> 2, wn = wave & 3;
    int mT, nT, z;
    if (swz == 1) {
        // GEMM1: 256 blocks. XCD = z = L&7 (one K-slice per XCD). Within XCD:
        // nT fastest (B working set L2-resident), A-panel read once.
        z = blockIdx.x & 7; int r = blockIdx.x >> 3; nT = r & 3; mT = r >> 2;
    } else {
        // GEMM2: 352 blocks. x = XCD; mT fastest within fixed nT (B-panel
        // reused 8x consecutively from L2). Tail nT=40..43 split across x.
        int x = blockIdx.x & 7, j = blockIdx.x >> 3;
        int nti = j >> 3; mT = j & 7;
        if (nti < 5)      nT = nti * 8 + x;
        else if (x < 4)   nT = 40 + x;              // mT = j&7 in 0..3
        else            { nT = 40 + (x - 4); mT = (j & 7) + 4; }
        z = 0;
    }
    const int m0 = mT * 256, n0 = nT * 256;
    const size_t kOff = (size_t)z * kLen;
    const int nTi = kLen >> 6;          // K-64 tiles, >= 2

    const int chl = ((tid & 3) ^ ((tid >> 3) & 3)) * 8;
    const u16* aB = A + (size_t)(m0 + (tid >> 2)) * ldA + kOff + chl;
    const u16* bB = B + (size_t)(n0 + (tid >> 2)) * ldB + kOff + chl;
    const size_t aH = (size_t)128 * ldA;
    const size_t bH = (size_t)128 * ldB;

    const int ml = lane & 15, kq8 = lane >> 4;
    const int kqs = (kq8 ^ ((ml >> 1) & 3)) * 8;
    const int aro = (wm * 128 + ml) * 32 + kqs;
    const int bro = (wn * 64 + ml) * 32 + kqs;

    f32x4 acc[8][4];
#pragma unroll
    for (int f = 0; f < 8; f++)
#pragma unroll
        for (int g = 0; g < 4; g++) acc[f][g] = (f32x4){0.f, 0.f, 0.f, 0.f};
    bf16x8 a[8], b[4], b2[4];

    // prologue: stage tile 0 fully, drain, barrier
    STG_A(0, 0, 0, 0); STG_A(0, 0, 1, 0); STG_A(0, 1, 0, 0); STG_A(0, 1, 1, 0);
    STG_B(0, 0, 0, 0); STG_B(0, 0, 1, 0); STG_B(0, 1, 0, 0); STG_B(0, 1, 1, 0);
    VMCNT0;
    BARX();

    for (int t = 0; t < nTi; t++) {
        const int p = t & 1, p1 = p ^ 1;
        const int kb1 = (t + 1) << 6;
        const bool s1 = (t + 1) < nTi;
        // phase 0: a(f0..3), b(g0..1); stage ALL of t+1's A
#pragma unroll
        for (int f = 0; f < 4; f++) {
            a[2*f]   = *(const bf16x8*)&As[p][0][aro + f * 512];
            a[2*f+1] = *(const bf16x8*)&As[p][1][aro + f * 512];
        }
#pragma unroll
        for (int g = 0; g < 2; g++) {
            b[2*g]   = *(const bf16x8*)&Bs[p][0][bro + g * 512];
            b[2*g+1] = *(const bf16x8*)&Bs[p][1][bro + g * 512];
        }
        if (s1) {
            STG_A(p1, 0, 0, kb1); STG_A(p1, 0, 1, kb1);
            STG_A(p1, 1, 0, kb1); STG_A(p1, 1, 1, kb1);
        }
        BARX();
        __builtin_amdgcn_s_setprio(1);
        MMQ(0, 0, b);
        __builtin_amdgcn_s_setprio(0);
        BARX();
        // phase 1: b2(g2..3); stage ALL of t+1's B
#pragma unroll
        for (int g = 0; g < 2; g++) {
            b2[2*g]   = *(const bf16x8*)&Bs[p][0][bro + (g + 2) * 512];
            b2[2*g+1] = *(const bf16x8*)&Bs[p][1][bro + (g + 2) * 512];
        }
        if (s1) {
            STG_B(p1, 0, 0, kb1); STG_B(p1, 0, 1, kb1);
            STG_B(p1, 1, 0, kb1); STG_B(p1, 1, 1, kb1);
        }
        BARX();
        __builtin_amdgcn_s_setprio(1);
        MMQ(0, 2, b2);
        __builtin_amdgcn_s_setprio(0);
        BARX();
        // phase 2: a(f4..7); no staging
#pragma unroll
        for (int f = 0; f < 4; f++) {
            a[2*f]   = *(const bf16x8*)&As[p][0][aro + (f + 4) * 512];
            a[2*f+1] = *(const bf16x8*)&As[p][1][aro + (f + 4) * 512];
        }
        BARX();
        __builtin_amdgcn_s_setprio(1);
        MMQ(4, 0, b);
        __builtin_amdgcn_s_setprio(0);
        BARX();
        // phase 3: no reads, no staging; tile-boundary drain (well covered)
        __builtin_amdgcn_s_setprio(1);
        MMQ(4, 2, b2);
        __builtin_amdgcn_s_setprio(0);
        if (s1) VMCNT0;
        BARX();
    }

    const int q = lane >> 4, nl = lane & 15;
    if (Cpart) {
        float* outP = Cpart + (size_t)z * Mtot * ldC;
#pragma unroll
        for (int f = 0; f < 8; f++)
#pragma unroll
            for (int g = 0; g < 4; g++)
#pragma unroll
                for (int reg = 0; reg < 4; reg++) {
                    int row = m0 + wm * 128 + f * 16 + q * 4 + reg;
                    int col = n0 + wn * 64 + g * 16 + nl;
                    outP[(size_t)row * ldC + col] = acc[f][g][reg];
                }
    } else {
#pragma unroll
        for (int f = 0; f < 8; f++)
#pragma unroll
            for (int g = 0; g < 4; g++)
#pragma unroll
                for (int reg = 0; reg < 4; reg++) {
                    int row = m0 + wm * 128 + f * 16 + q * 4 + reg;
                    int col = n0 + wn * 64 + g * 16 + nl;
                    float v = acc[f][g][reg] * scale + (bias ? bias[col] : 0.0f);
                    Cb[(size_t)row * ldC + col] = f2bf(v);
                }
    }
}

// sum split-K partials + epilogue
__global__ __launch_bounds__(256) void k_reduce(const float* __restrict__ part, size_t stride,
                                                int SK, int total, int N, float scale,
                                                const float* __restrict__ bias,
                                                float* __restrict__ outF, u16* __restrict__ outB) {
    int i = blockIdx.x * 256 + threadIdx.x;
    if (i >= total) return;
    float s = 0.f;
    for (int z = 0; z < SK; z++) s += part[(size_t)z * stride + i];
    float v = s * scale + (bias ? bias[i % N] : 0.0f);
    if (outF) outF[i] = v;
    else      outB[i] = f2bf(v);
}

// ---------------------------------------------------------------- rowwise LN
__device__ __forceinline__ float blockReduce(float v, float* red) {
#pragma unroll
    for (int off = 32; off > 0; off >>= 1) v += __shfl_down(v, off);
    __syncthreads();
    if ((threadIdx.x & 63) == 0) red[threadIdx.x >> 6] = v;
    __syncthreads();
    return red[0] + red[1] + red[2] + red[3];
}

__global__ __launch_bounds__(256) void k_ln_fwd(const float* __restrict__ X, int D,
    const float* __restrict__ g, const float* __restrict__ be,
    float* __restrict__ mu_out, float* __restrict__ r_out,
    u16* __restrict__ a_bf, float* __restrict__ a_f32) {
    __shared__ float red[4];
    int b = blockIdx.x, tid = threadIdx.x;
    const float* x = X + (size_t)b * D;
    int nd = D >> 8;
    float s = 0.f, s2 = 0.f;
    for (int r = 0; r < nd; r++) { float v = x[tid + (r << 8)]; s += v; s2 += v * v; }
    s = blockReduce(s, red);
    s2 = blockReduce(s2, red);
    float mu = s / D;
    float var = s2 / D - mu * mu;
    float rst = rsqrtf(var + 1e-6f);
    if (tid == 0) { mu_out[b] = mu; r_out[b] = rst; }
    for (int r = 0; r < nd; r++) {
        int i = tid + (r << 8);
        float xh = (x[i] - mu) * rst;
        float ln = xh * g[i] + be[i];
        float a = ln / (1.0f + expf(-ln));
        if (a_bf)  a_bf[(size_t)b * D + i] = f2bf(a);
        if (a_f32) a_f32[(size_t)b * D + i] = a;
    }
}

__global__ __launch_bounds__(256) void k_ln_bwd(const float* __restrict__ dup,
    const float* __restrict__ X, const float* __restrict__ mu_in, const float* __restrict__ r_in,
    const float* __restrict__ g, const float* __restrict__ be,
    u16* __restrict__ out_bf, int D) {
    __shared__ float red[4];
    int b = blockIdx.x, tid = threadIdx.x;
    const float* x = X + (size_t)b * D;
    float mu = mu_in[b], rst = r_in[b];
    int nd = D >> 8;
    float w_[4], xh_[4];
    float sw = 0.f, swx = 0.f;
    for (int r = 0; r < nd; r++) {
        int i = tid + (r << 8);
        float xh = (x[i] - mu) * rst;
        float ln = xh * g[i] + be[i];
        float sg = 1.0f / (1.0f + expf(-ln));
        float dsilu = sg * (1.0f + ln * (1.0f - sg));
        float d = dup ? dup[(size_t)b * D + i] : 1.0f;
        float w = g[i] * dsilu * d;
        w_[r] = w; xh_[r] = xh;
        sw += w; swx += w * xh;
    }
    sw = blockReduce(sw, red);
    swx = blockReduce(swx, red);
    float invD = 1.0f / D;
    for (int r = 0; r < nd; r++) {
        int i = tid + (r << 8);
        float dx = rst * (w_[r] - sw * invD - xh_[r] * swx * invD);
        out_bf[(size_t)b * D + i] = f2bf(dx);
    }
}

// ---------------------------------------------------------------- packed contraction
__global__ __launch_bounds__(256) void k_contract_p(const u16* __restrict__ Gp,
                                                    const float* __restrict__ t,
                                                    float* __restrict__ y) {
    __shared__ u16 gp_s[NPACK];
    __shared__ float xs[480];
    int b = blockIdx.x, tid = threadIdx.x;
    const uint4* gsrc = (const uint4*)(Gp + (size_t)b * NPACK);
    for (int j = tid; j < NPACK / 8; j += 256) ((uint4*)gp_s)[j] = gsrc[j];
    for (int j = tid; j < 480; j += 256) xs[j] = t[(size_t)b * 480 + j];
    __syncthreads();
    int wave = tid >> 6, lane = tid & 63;
    float* yr = y + (size_t)b * 480;
    for (int r = 0; r < 32; r++) {
        int u = wave * 32 + r;
        int v0 = lane, v1 = lane + 64;
        float s = bf2f(gp_s[pk0(u, v0)]) * xs[v0] + bf2f(gp_s[pk0(u, v1)]) * xs[v1];
#pragma unroll
        for (int off = 32; off > 0; off >>= 1) s += __shfl_down(s, off);
        if (lane == 0) yr[u] = s;
    }
    for (int r = 0; r < 16; r++) {
        int u = wave * 16 + r;
        float gv = bf2f(gp_s[pk1(u, lane)]);
        float a0 = gv * xs[128 + lane * 3 + 0];
        float a1 = gv * xs[128 + lane * 3 + 1];
        float a2 = gv * xs[128 + lane * 3 + 2];
#pragma unroll
        for (int off = 32; off > 0; off >>= 1) {
            a0 += __shfl_down(a0, off);
            a1 += __shfl_down(a1, off);
            a2 += __shfl_down(a2, off);
        }
        if (lane == 0) {
            yr[128 + u * 3 + 0] = a0;
            yr[128 + u * 3 + 1] = a1;
            yr[128 + u * 3 + 2] = a2;
        }
    }
    for (int r = 0; r < 8; r++) {
        int u = wave * 8 + r;
        bool act = lane < 32;
        float gv = act ? bf2f(gp_s[pk2(u, act ? lane : 0)]) : 0.f;
        float a[5];
#pragma unroll
        for (int m = 0; m < 5; m++)
            a[m] = act ? gv * xs[320 + lane * 5 + m] : 0.f;
#pragma unroll
        for (int off = 32; off > 0; off >>= 1)
#pragma unroll
            for (int m = 0; m < 5; m++) a[m] += __shfl_down(a[m], off);
        if (lane == 0)
#pragma unroll
            for (int m = 0; m < 5; m++) yr[320 + u * 5 + m] = a[m];
    }
}

// ---------------------------------------------------------------- launch
extern "C" void kernel_launch(void* const* d_in, const int* in_sizes, int n_in,
                              void* d_out, int out_size, void* d_ws, size_t ws_size,
                              hipStream_t stream) {
    const float* t   = (const float*)d_in[0];
    const float* w0  = (const float*)d_in[1];
    const float* w1  = (const float*)d_in[2];
    const float* w2  = (const float*)d_in[3];
    const float* W1  = (const float*)d_in[4];
    const float* b1  = (const float*)d_in[5];
    const float* g1  = (const float*)d_in[6];
    const float* be1 = (const float*)d_in[7];
    const float* W2  = (const float*)d_in[8];
    const float* b2  = (const float*)d_in[9];
    const float* g2  = (const float*)d_in[10];
    const float* be2 = (const float*)d_in[11];

    float* xout = (float*)d_out;                    // 2048*256
    float* yout = xout + (size_t)2048 * 256;        // 2048*480

    char* ws = (char*)d_ws;
    size_t off = 0;
    auto alloc = [&](size_t bytes) -> void* {
        void* p = ws + off;
        off += (bytes + 255) & ~(size_t)255;
        return p;
    };
    u16*   PG    = (u16*)alloc((size_t)2048 * NPACK * 2);   // Ppack, later Gp (aliased)
    u16*   Wsym  = (u16*)alloc((size_t)NPACK * 1024 * 2);   // packed Wsym [i,h]
    u16*   Wt    = (u16*)alloc((size_t)1024 * NPACK * 2);   // packed Wsym^T [h,i]
    u16*   uvtab = (u16*)alloc((size_t)NPACK * 2);
    u16*   W1b   = (u16*)alloc((size_t)1024 * 1024 * 2);
    u16*   W1tb  = (u16*)alloc((size_t)1024 * 1024 * 2);
    u16*   W2b   = (u16*)alloc((size_t)1024 * 256 * 2);
    u16*   W2tb  = (u16*)alloc((size_t)256 * 1024 * 2);
    u16*   h_bf  = (u16*)alloc((size_t)2048 * 1024 * 2);
    float* h1pre = (float*)alloc((size_t)2048 * 1024 * 4);
    float* mu1   = (float*)alloc(2048 * 4);
    float* r1    = (float*)alloc(2048 * 4);
    u16*   a1_bf = (u16*)alloc((size_t)2048 * 1024 * 2);
    float* h2pre = (float*)alloc((size_t)2048 * 256 * 4);
    float* mu2   = (float*)alloc(2048 * 4);
    float* r2    = (float*)alloc(2048 * 4);
    u16*   dh2b  = (u16*)alloc((size_t)2048 * 256 * 2);
    float* d_a1  = (float*)alloc((size_t)2048 * 1024 * 4);
    u16*   dh1b  = (u16*)alloc((size_t)2048 * 1024 * 2);
    u16*   de_bf = (u16*)alloc((size_t)2048 * 1024 * 2);
    float* Cpart = (float*)(ws + off);
    size_t cpartBytes = (ws_size > off) ? (ws_size - off) : 0;
    (void)in_sizes; (void)n_in; (void)out_size;

    const float sF = 1.0f / sqrtf(21504.0f);

    // generic GEMM helper (MLP GEMMs): 3-D grid, optional split-K
    auto gemm = [&](const u16* A, int ldA, const u16* B, int ldB, int M, int N, int K,
                    int SKwant, float scale, const float* bias,
                    float* Cf, u16* Cb, int ldC) {
        int SK = SKwant;
        size_t slice = (size_t)M * ldC * 4;
        if (SK > 1 && cpartBytes < 2 * slice) SK = 1;
        if (SK > 1 && (size_t)SK * slice > cpartBytes) SK = (int)(cpartBytes / slice);
        while (SK > 1 && !((K % SK) == 0 && ((K / SK) % 64) == 0)) SK--;
        dim3 grid(N / 128, M / 128, SK);
        if (SK > 1) {
            k_gemm2<<<grid, 256, 0, stream>>>(A, ldA, B, ldB, K / SK, 0.f, nullptr,
                                              nullptr, nullptr, ldC, Cpart, M, 0);
            int total = M * ldC;
            k_reduce<<<(total + 255) / 256, 256, 0, stream>>>(Cpart, (size_t)M * ldC, SK,
                                                              total, N, scale, bias, Cf, Cb);
        } else {
            k_gemm2<<<grid, 256, 0, stream>>>(A, ldA, B, ldB, K, scale, bias,
                                              Cf, Cb, ldC, nullptr, M, 0);
        }
    };

    // index table + packed weights
    k_uvall<<<(21504 + NPACK - NVALID + 255) / 256, 256, 0, stream>>>(uvtab);
    k_packw<<<dim3(NPACK / 32, 4), 256, 0, stream>>>(w0, w1, w2, uvtab, Wsym, Wt);

    // small MLP weights
    k_transpose<<<dim3(32, 32), 256, 0, stream>>>(W1, 1024, 1024, W1tb, 1024);
    k_transpose<<<dim3(8, 32), 256, 0, stream>>>(W2, 1024, 256, W2tb, 1024);
    k_convert<<<1024 * 1024 / 1024, 256, 0, stream>>>(W1, W1b, 1024 * 1024 / 4);
    k_convert<<<1024 * 256 / 1024, 256, 0, stream>>>(W2, W2b, 1024 * 256 / 4);

    // packed features
    k_features_pack<<<2048, 256, 0, stream>>>(t, uvtab, PG);

    // GEMM1: h = sF * Ppack @ Wt^T. 256-tile: 8z x (4nT x 8mT) = 256 blocks, kLen=1408.
    k_gemm256<<<dim3(256), 512, 0, stream>>>(PG, NPACK, Wt, NPACK, NPACK / 8, 0.f, nullptr,
                                             nullptr, 1024, Cpart, 2048, 1);
    {
        int total = 2048 * 1024;
        k_reduce<<<(total + 255) / 256, 256, 0, stream>>>(Cpart, (size_t)2048 * 1024, 8,
                                                          total, 1024, sF, nullptr,
                                                          nullptr, h_bf);
    }

    // MLP forward
    gemm(h_bf, 1024, W1tb, 1024, 2048, 1024, 1024, 4, 1.0f, b1, h1pre, nullptr, 1024);
    k_ln_fwd<<<2048, 256, 0, stream>>>(h1pre, 1024, g1, be1, mu1, r1, a1_bf, nullptr);
    gemm(a1_bf, 1024, W2tb, 1024, 2048, 256, 1024, 8, 1.0f, b2, h2pre, nullptr, 256);
    k_ln_fwd<<<2048, 256, 0, stream>>>(h2pre, 256, g2, be2, mu2, r2, nullptr, xout);

    // backward
    k_ln_bwd<<<2048, 256, 0, stream>>>(nullptr, h2pre, mu2, r2, g2, be2, dh2b, 256);
    gemm(dh2b, 256, W2b, 256, 2048, 1024, 256, 4, 1.0f, nullptr, d_a1, nullptr, 1024);
    k_ln_bwd<<<2048, 256, 0, stream>>>(d_a1, h1pre, mu1, r1, g1, be1, dh1b, 1024);
    gemm(dh1b, 1024, W1b, 1024, 2048, 1024, 1024, 4, sF, nullptr, nullptr, de_bf, 1024);

    // GEMM2: Gp = de @ Wsym^T. 256-tile: 352 blocks, K=1024, XCD-local B reuse.
    u16* Gp = PG;   // Ppack dead after GEMM1
    k_gemm256<<<dim3(352), 512, 0, stream>>>(de_bf, 1024, Wsym, 1024, 1024, 1.0f, nullptr,
                                             Gp, NPACK, nullptr, 2048, 2);

    // y from packed symmetric Gp (shuffle-reduce, no atomics)
    k_contract_p<<<2048, 256, 0, stream>>>(Gp, t, yout);
}

// Round 6
// 501.085 us; speedup vs baseline: 1.0792x; 1.0591x over previous
//
#include <hip/hip_runtime.h>
#include <math.h>

typedef unsigned short u16;
typedef __bf16 bf16x8 __attribute__((ext_vector_type(8)));
typedef float f32x4 __attribute__((ext_vector_type(4)));

#define NPACK  11264   // padded packed-pair count (88*128)
#define NVALID 10864   // 8256 + 2080 + 528
#define BASE1  8256
#define BASE2  10336

__device__ __forceinline__ u16 f2bf(float f) {
    unsigned u = __builtin_bit_cast(unsigned, f);
    u += 0x7FFFu + ((u >> 16) & 1u);
    return (u16)(u >> 16);
}
__device__ __forceinline__ float bf2f(u16 h) {
    return __builtin_bit_cast(float, ((unsigned)h) << 16);
}

#define GLOAD_LDS16(g, l)                                                     \
    __builtin_amdgcn_global_load_lds(                                         \
        (const __attribute__((address_space(1))) void*)(g),                   \
        (__attribute__((address_space(3))) void*)(l), 16, 0, 0)

// packed triangular index (u<=v), per segment
__device__ __forceinline__ int pk0(int a, int b) {
    int u = min(a, b), v = max(a, b);
    return u * 128 - (u * (u - 1)) / 2 + (v - u);
}
__device__ __forceinline__ int pk1(int a, int b) {
    int u = min(a, b), v = max(a, b);
    return BASE1 + u * 64 - (u * (u - 1)) / 2 + (v - u);
}
__device__ __forceinline__ int pk2(int a, int b) {
    int u = min(a, b), v = max(a, b);
    return BASE2 + u * 32 - (u * (u - 1)) / 2 + (v - u);
}

// ---------------------------------------------------------------- fused prep
// Range-dispatched: uv table + W1/W2 transpose + W1/W2 convert in ONE launch
// (replaces 5 small kernels; all parts independent).
// bid <  86    : uv table
// 86..1109     : transpose W1 (32x32 tiles, grid 32x32)
// 1110..1365   : transpose W2 (grid 8x32)
// 1366..2389   : convert W1 (1024 blocks)
// 2390..2645   : convert W2 (256 blocks)
__device__ __forceinline__ void prep_transpose(const float* __restrict__ in, int C,
                                               u16* __restrict__ out, int ldOut,
                                               int bx, int by, int tid) {
    __shared__ float tile[32][33];
    int tr0 = by * 32, tc0 = bx * 32;
    int lr = tid >> 5, lc = tid & 31;
#pragma unroll
    for (int i = 0; i < 4; i++) {
        int rr = lr + i * 8;
        tile[rr][lc] = in[(size_t)(tr0 + rr) * C + tc0 + lc];
    }
    __syncthreads();
#pragma unroll
    for (int i = 0; i < 4; i++) {
        int rr = lr + i * 8;
        out[(size_t)(tc0 + rr) * ldOut + tr0 + lc] = f2bf(tile[lc][rr]);
    }
}
__device__ __forceinline__ void prep_convert(const float* __restrict__ in,
                                             u16* __restrict__ out, int i, int n4) {
    if (i >= n4) return;
    float4 v = ((const float4*)in)[i];
    union { u16 a[4]; unsigned long long q; } o;
    o.a[0] = f2bf(v.x); o.a[1] = f2bf(v.y); o.a[2] = f2bf(v.z); o.a[3] = f2bf(v.w);
    ((unsigned long long*)out)[i] = o.q;
}

__global__ __launch_bounds__(256) void k_prep(u16* __restrict__ tab,
                                              const float* __restrict__ W1,
                                              const float* __restrict__ W2,
                                              u16* __restrict__ W1b,
                                              u16* __restrict__ W1tb,
                                              u16* __restrict__ W2b,
                                              u16* __restrict__ W2tb) {
    int bid = blockIdx.x, tid = threadIdx.x;
    if (bid < 86) {
        int j = bid * 256 + tid;
        if (j < 16384) {
            int u = j >> 7, v = j & 127;
            if (v >= u) tab[pk0(u, v)] = (u16)((u << 7) | v);
        } else if (j < 20480) {
            int k = j - 16384, u = k >> 6, v = k & 63;
            if (v >= u) tab[pk1(u, v)] = (u16)((1 << 14) | (u << 7) | v);
        } else if (j < 21504) {
            int k = j - 20480, u = k >> 5, v = k & 31;
            if (v >= u) tab[pk2(u, v)] = (u16)((2 << 14) | (u << 7) | v);
        } else if (j < 21504 + (NPACK - NVALID)) {
            tab[NVALID + (j - 21504)] = 0xFFFFu;
        }
    } else if (bid < 1110) {
        int k = bid - 86;                       // grid 32x32
        prep_transpose(W1, 1024, W1tb, 1024, k & 31, k >> 5, tid);
    } else if (bid < 1366) {
        int k = bid - 1110;                     // grid 8x32
        prep_transpose(W2, 256, W2tb, 1024, k & 7, k >> 3, tid);
    } else if (bid < 2390) {
        prep_convert(W1, W1b, (bid - 1366) * 256 + tid, 1024 * 1024 / 4);
    } else {
        prep_convert(W2, W2b, (bid - 2390) * 256 + tid, 1024 * 256 / 4);
    }
}

// ---------------------------------------------------------------- packed weights
__global__ __launch_bounds__(256) void k_packw(const float* __restrict__ w0,
                                               const float* __restrict__ w1,
                                               const float* __restrict__ w2,
                                               const u16* __restrict__ tab,
                                               u16* __restrict__ Wsym,
                                               u16* __restrict__ Wt) {
    __shared__ u16 tile[32][258];
    __shared__ u16 te[32];
    int i0 = blockIdx.x * 32, h0 = blockIdx.y * 256, tid = threadIdx.x;
    if (tid < 32) te[tid] = tab[i0 + tid];
    __syncthreads();
    const float s1 = 0.57735026918962576f, s2 = 0.44721359549995794f;
    for (int il = 0; il < 32; il++) {
        unsigned e = te[il];
        float val = 0.f;
        if ((e >> 14) != 3) {
            int seg = e >> 14, u = (e >> 7) & 127, v = e & 127;
            const float* wb; int S; float sc;
            if (seg == 0)      { wb = w0; S = 128; sc = 1.f; }
            else if (seg == 1) { wb = w1; S = 64;  sc = s1; }
            else               { wb = w2; S = 32;  sc = s2; }
            val = sc * (wb[(size_t)(u * S + v) * 1024 + h0 + tid] +
                        wb[(size_t)(v * S + u) * 1024 + h0 + tid]);
        }
        u16 bv = f2bf(val);
        Wsym[(size_t)(i0 + il) * 1024 + h0 + tid] = bv;
        tile[il][tid] = bv;
    }
    __syncthreads();
    union { u16 a[32]; uint4 q[4]; } pk;
#pragma unroll
    for (int il = 0; il < 32; il++) pk.a[il] = tile[il][tid];
    uint4* dst = (uint4*)(Wt + (size_t)(h0 + tid) * NPACK + i0);
#pragma unroll
    for (int q = 0; q < 4; q++) dst[q] = pk.q[q];
}

// ---------------------------------------------------------------- packed features
__global__ __launch_bounds__(256) void k_features_pack(const float* __restrict__ t,
                                                       const u16* __restrict__ tab,
                                                       u16* __restrict__ P) {
    __shared__ u16 tab_s[NPACK];
    __shared__ float tr[480];
    int b = blockIdx.x, tid = threadIdx.x;
    for (int j = tid; j < NPACK / 8; j += 256)
        ((uint4*)tab_s)[j] = ((const uint4*)tab)[j];
    for (int j = tid; j < 480; j += 256) tr[j] = t[(size_t)b * 480 + j];
    __syncthreads();
    u16* row = P + (size_t)b * NPACK;
    for (int i = tid; i < NPACK; i += 256) {
        unsigned e = tab_s[i];
        float p = 0.f;
        if ((e >> 14) != 3) {
            int seg = e >> 14, u = (e >> 7) & 127, v = e & 127;
            if (seg == 0) p = tr[u] * tr[v];
            else if (seg == 1) {
                const float* x1 = tr + 128;
                p = x1[u*3]*x1[v*3] + x1[u*3+1]*x1[v*3+1] + x1[u*3+2]*x1[v*3+2];
            } else {
                const float* x2 = tr + 320;
#pragma unroll
                for (int m = 0; m < 5; m++) p += x2[u*5+m] * x2[v*5+m];
            }
            if (u == v) p *= 0.5f;
        }
        row[i] = f2bf(p);
    }
}

// ---------------------------------------------------------------- GEMM 128-tile (MLP sizes)
// Split-K partials stored as bf16 (halves Cpart HBM traffic; partial magnitude
// ~0.35x final so added rounding ~2e-3 rel, below bf16-input noise).
__global__ __launch_bounds__(256) void k_gemm2(const u16* __restrict__ A, int ldA,
                                               const u16* __restrict__ B, int ldB,
                                               int kLen, float scale,
                                               const float* __restrict__ bias,
                                               float* __restrict__ Cf,
                                               u16* __restrict__ Cb, int ldC,
                                               u16* __restrict__ Cpart, int Mtot,
                                               int swz) {
    __shared__ u16 As[2][128 * 32];
    __shared__ u16 Bs[2][128 * 32];
    const int tid = threadIdx.x;
    const int wave = tid >> 6, lane = tid & 63;
    const int wm = wave >> 1, wn = wave & 1;
    int nT, mT, z;
    if (swz == 1) {
        int L = blockIdx.x;
        z = L & 7; int r = L >> 3;
        nT = r >> 4; mT = r & 15;
    } else if (swz == 2) {
        int L = blockIdx.x;
        int c = L & 7, r = L >> 3;
        nT = (r % 11) * 8 + c; mT = r / 11; z = 0;
    } else {
        nT = blockIdx.x; mT = blockIdx.y; z = blockIdx.z;
    }
    const int m0 = mT * 128, n0 = nT * 128;
    const size_t kOff = (size_t)z * kLen;

    const int chl = (((lane & 3) ^ ((lane >> 3) & 3))) * 8;
    const u16* aG = A + (size_t)(m0 + wave * 32 + (lane >> 2)) * ldA + kOff + chl;
    const u16* bG = B + (size_t)(n0 + wave * 32 + (lane >> 2)) * ldB + kOff + chl;
    const size_t aS = (size_t)16 * ldA;
    const size_t bS = (size_t)16 * ldB;
    u16* aL0 = &As[0][(wave * 32) * 32];
    u16* aL1 = &As[0][(wave * 32 + 16) * 32];
    u16* aH0 = &As[1][(wave * 32) * 32];
    u16* aH1 = &As[1][(wave * 32 + 16) * 32];
    u16* bL0 = &Bs[0][(wave * 32) * 32];
    u16* bL1 = &Bs[0][(wave * 32 + 16) * 32];
    u16* bH0 = &Bs[1][(wave * 32) * 32];
    u16* bH1 = &Bs[1][(wave * 32 + 16) * 32];

    f32x4 acc[4][4];
#pragma unroll
    for (int i = 0; i < 4; i++)
#pragma unroll
        for (int j = 0; j < 4; j++) acc[i][j] = (f32x4){0.f, 0.f, 0.f, 0.f};

    const int ml = lane & 15, kq8 = lane >> 4;
    const int kqs = (kq8 ^ ((ml >> 1) & 3)) * 8;
    const u16* aRd0 = &As[0][(wm * 64 + ml) * 32 + kqs];
    const u16* bRd0 = &Bs[0][(wn * 64 + ml) * 32 + kqs];
    const u16* aRd1 = &As[1][(wm * 64 + ml) * 32 + kqs];
    const u16* bRd1 = &Bs[1][(wn * 64 + ml) * 32 + kqs];

    for (int k = 0; k < kLen; k += 64) {
        GLOAD_LDS16(aG, aL0);
        GLOAD_LDS16(aG + aS, aL1);
        GLOAD_LDS16(aG + 32, aH0);
        GLOAD_LDS16(aG + aS + 32, aH1);
        GLOAD_LDS16(bG, bL0);
        GLOAD_LDS16(bG + bS, bL1);
        GLOAD_LDS16(bG + 32, bH0);
        GLOAD_LDS16(bG + bS + 32, bH1);
        aG += 64; bG += 64;
        __syncthreads();
        {
            bf16x8 af[4], bfv[4];
#pragma unroll
            for (int i = 0; i < 4; i++) af[i]  = *(const bf16x8*)(aRd0 + i * 16 * 32);
#pragma unroll
            for (int j = 0; j < 4; j++) bfv[j] = *(const bf16x8*)(bRd0 + j * 16 * 32);
#pragma unroll
            for (int i = 0; i < 4; i++)
#pragma unroll
                for (int j = 0; j < 4; j++)
                    acc[i][j] = __builtin_amdgcn_mfma_f32_16x16x32_bf16(af[i], bfv[j], acc[i][j], 0, 0, 0);
        }
        {
            bf16x8 af[4], bfv[4];
#pragma unroll
            for (int i = 0; i < 4; i++) af[i]  = *(const bf16x8*)(aRd1 + i * 16 * 32);
#pragma unroll
            for (int j = 0; j < 4; j++) bfv[j] = *(const bf16x8*)(bRd1 + j * 16 * 32);
#pragma unroll
            for (int i = 0; i < 4; i++)
#pragma unroll
                for (int j = 0; j < 4; j++)
                    acc[i][j] = __builtin_amdgcn_mfma_f32_16x16x32_bf16(af[i], bfv[j], acc[i][j], 0, 0, 0);
        }
        __syncthreads();
    }

    const int q = lane >> 4, nl = lane & 15;
    if (Cpart) {
        u16* outP = Cpart + (size_t)z * Mtot * ldC;
#pragma unroll
        for (int i = 0; i < 4; i++)
#pragma unroll
            for (int j = 0; j < 4; j++)
#pragma unroll
                for (int reg = 0; reg < 4; reg++) {
                    int row = m0 + wm * 64 + i * 16 + q * 4 + reg;
                    int col = n0 + wn * 64 + j * 16 + nl;
                    outP[(size_t)row * ldC + col] = f2bf(acc[i][j][reg]);
                }
    } else {
#pragma unroll
        for (int i = 0; i < 4; i++)
#pragma unroll
            for (int j = 0; j < 4; j++)
#pragma unroll
                for (int reg = 0; reg < 4; reg++) {
                    int row = m0 + wm * 64 + i * 16 + q * 4 + reg;
                    int col = n0 + wn * 64 + j * 16 + nl;
                    float v = acc[i][j][reg] * scale + (bias ? bias[col] : 0.0f);
                    if (Cf) Cf[(size_t)row * ldC + col] = v;
                    else    Cb[(size_t)row * ldC + col] = f2bf(v);
                }
    }
}

// ---------------------------------------------------------------- GEMM 256-tile, 8-wave, quadrant phases
// R3 schedule (best measured). bf16 split-K partials.
//  ph0: rd a[8](f0..3,kh01) + b[4](g0..1,kh01); STG_A kh0 -> MFMA f0..3 x g0..1
//  ph1: rd b2[4](g2..3,kh01);                   STG_A kh1 -> MFMA f0..3 x g2..3
//  ph2: rd a[8](f4..7,kh01);                    STG_B kh0 -> MFMA f4..7 x g0..1
//  ph3: no reads;                               STG_B kh1 -> MFMA f4..7 x g2..3
//  vmcnt(0)+barrier at tile boundary only.
#define VMCNT0 asm volatile("s_waitcnt vmcnt(0)" ::: "memory")
#define BARX() __builtin_amdgcn_s_barrier()

#define STG_A(p, kh, rh, kb) GLOAD_LDS16(aB + (size_t)(rh) * aH + (kb) + (kh) * 32, \
                                         &As[p][kh][((rh) * 128 + wave * 16) * 32])
#define STG_B(p, kh, rh, kb) GLOAD_LDS16(bB + (size_t)(rh) * bH + (kb) + (kh) * 32, \
                                         &Bs[p][kh][((rh) * 128 + wave * 16) * 32])
#define MMQ(fb, gb, bv) do { _Pragma("unroll") \
    for (int ff = 0; ff < 4; ff++) { _Pragma("unroll") \
        for (int gg = 0; gg < 2; gg++) { \
            acc[(fb)+ff][(gb)+gg] = __builtin_amdgcn_mfma_f32_16x16x32_bf16(a[2*ff],   bv[2*gg],   acc[(fb)+ff][(gb)+gg], 0, 0, 0); \
            acc[(fb)+ff][(gb)+gg] = __builtin_amdgcn_mfma_f32_16x16x32_bf16(a[2*ff+1], bv[2*gg+1], acc[(fb)+ff][(gb)+gg], 0, 0, 0); } } } while (0)

__global__ __launch_bounds__(512, 2) void k_gemm256(const u16* __restrict__ A, int ldA,
                                                    const u16* __restrict__ B, int ldB,
                                                    int kLen, float scale,
                                                    const float* __restrict__ bias,
                                                    u16* __restrict__ Cb, int ldC,
                                                    u16* __restrict__ Cpart, int Mtot,
                                                    int swz) {
    __shared__ __align__(16) u16 As[2][2][256 * 32];   // [buf][kh][row*32+k]  64 KB
    __shared__ __align__(16) u16 Bs[2][2][256 * 32];   // 64 KB
    const int tid = threadIdx.x;
    const int lane = tid & 63, wave = tid >> 6;
    const int wm = wave >> 2, wn = wave & 3;
    int mT, nT, z;
    if (swz == 1) {
        // GEMM1: 256 blocks. XCD = z = L&7. Within XCD: nT fastest.
        z = blockIdx.x & 7; int r = blockIdx.x >> 3; nT = r & 3; mT = r >> 2;
    } else {
        // GEMM2: 352 blocks. x = XCD; mT fastest within fixed nT.
        int x = blockIdx.x & 7, j = blockIdx.x >> 3;
        int nti = j >> 3; mT = j & 7;
        if (nti < 5)      nT = nti * 8 + x;
        else if (x < 4)   nT = 40 + x;
        else            { nT = 40 + (x - 4); mT = (j & 7) + 4; }
        z = 0;
    }
    const int m0 = mT * 256, n0 = nT * 256;
    const size_t kOff = (size_t)z * kLen;
    const int nTi = kLen >> 6;          // K-64 tiles, >= 2

    const int chl = ((tid & 3) ^ ((tid >> 3) & 3)) * 8;
    const u16* aB = A + (size_t)(m0 + (tid >> 2)) * ldA + kOff + chl;
    const u16* bB = B + (size_t)(n0 + (tid >> 2)) * ldB + kOff + chl;
    const size_t aH = (size_t)128 * ldA;
    const size_t bH = (size_t)128 * ldB;

    const int ml = lane & 15, kq8 = lane >> 4;
    const int kqs = (kq8 ^ ((ml >> 1) & 3)) * 8;
    const int aro = (wm * 128 + ml) * 32 + kqs;
    const int bro = (wn * 64 + ml) * 32 + kqs;

    f32x4 acc[8][4];
#pragma unroll
    for (int f = 0; f < 8; f++)
#pragma unroll
        for (int g = 0; g < 4; g++) acc[f][g] = (f32x4){0.f, 0.f, 0.f, 0.f};
    bf16x8 a[8], b[4], b2[4];

    // prologue: stage tile 0 fully, drain, barrier
    STG_A(0, 0, 0, 0); STG_A(0, 0, 1, 0); STG_A(0, 1, 0, 0); STG_A(0, 1, 1, 0);
    STG_B(0, 0, 0, 0); STG_B(0, 0, 1, 0); STG_B(0, 1, 0, 0); STG_B(0, 1, 1, 0);
    VMCNT0;
    BARX();

    for (int t = 0; t < nTi; t++) {
        const int p = t & 1, p1 = p ^ 1;
        const int kb1 = (t + 1) << 6;
        const bool s1 = (t + 1) < nTi;
        // phase 0: a(f0..3), b(g0..1); stage t+1 A kh0
#pragma unroll
        for (int f = 0; f < 4; f++) {
            a[2*f]   = *(const bf16x8*)&As[p][0][aro + f * 512];
            a[2*f+1] = *(const bf16x8*)&As[p][1][aro + f * 512];
        }
#pragma unroll
        for (int g = 0; g < 2; g++) {
            b[2*g]   = *(const bf16x8*)&Bs[p][0][bro + g * 512];
            b[2*g+1] = *(const bf16x8*)&Bs[p][1][bro + g * 512];
        }
        if (s1) { STG_A(p1, 0, 0, kb1); STG_A(p1, 0, 1, kb1); }
        BARX();
        __builtin_amdgcn_s_setprio(1);
        MMQ(0, 0, b);
        __builtin_amdgcn_s_setprio(0);
        BARX();
        // phase 1: b2(g2..3); stage t+1 A kh1
#pragma unroll
        for (int g = 0; g < 2; g++) {
            b2[2*g]   = *(const bf16x8*)&Bs[p][0][bro + (g + 2) * 512];
            b2[2*g+1] = *(const bf16x8*)&Bs[p][1][bro + (g + 2) * 512];
        }
        if (s1) { STG_A(p1, 1, 0, kb1); STG_A(p1, 1, 1, kb1); }
        BARX();
        __builtin_amdgcn_s_setprio(1);
        MMQ(0, 2, b2);
        __builtin_amdgcn_s_setprio(0);
        BARX();
        // phase 2: a(f4..7); stage t+1 B kh0
#pragma unroll
        for (int f = 0; f < 4; f++) {
            a[2*f]   = *(const bf16x8*)&As[p][0][aro + (f + 4) * 512];
            a[2*f+1] = *(const bf16x8*)&As[p][1][aro + (f + 4) * 512];
        }
        if (s1) { STG_B(p1, 0, 0, kb1); STG_B(p1, 0, 1, kb1); }
        BARX();
        __builtin_amdgcn_s_setprio(1);
        MMQ(4, 0, b);
        __builtin_amdgcn_s_setprio(0);
        BARX();
        // phase 3: no reads; stage t+1 B kh1; tile-boundary drain
        if (s1) { STG_B(p1, 1, 0, kb1); STG_B(p1, 1, 1, kb1); }
        __builtin_amdgcn_s_setprio(1);
        MMQ(4, 2, b2);
        __builtin_amdgcn_s_setprio(0);
        if (s1) VMCNT0;
        BARX();
    }

    const int q = lane >> 4, nl = lane & 15;
    if (Cpart) {
        u16* outP = Cpart + (size_t)z * Mtot * ldC;
#pragma unroll
        for (int f = 0; f < 8; f++)
#pragma unroll
            for (int g = 0; g < 4; g++)
#pragma unroll
                for (int reg = 0; reg < 4; reg++) {
                    int row = m0 + wm * 128 + f * 16 + q * 4 + reg;
                    int col = n0 + wn * 64 + g * 16 + nl;
                    outP[(size_t)row * ldC + col] = f2bf(acc[f][g][reg]);
                }
    } else {
#pragma unroll
        for (int f = 0; f < 8; f++)
#pragma unroll
            for (int g = 0; g < 4; g++)
#pragma unroll
                for (int reg = 0; reg < 4; reg++) {
                    int row = m0 + wm * 128 + f * 16 + q * 4 + reg;
                    int col = n0 + wn * 64 + g * 16 + nl;
                    float v = acc[f][g][reg] * scale + (bias ? bias[col] : 0.0f);
                    Cb[(size_t)row * ldC + col] = f2bf(v);
                }
    }
}

// sum split-K bf16 partials + epilogue
__global__ __launch_bounds__(256) void k_reduce(const u16* __restrict__ part, size_t stride,
                                                int SK, int total, int N, float scale,
                                                const float* __restrict__ bias,
                                                float* __restrict__ outF, u16* __restrict__ outB) {
    int i = blockIdx.x * 256 + threadIdx.x;
    if (i >= total) return;
    float s = 0.f;
    for (int z = 0; z < SK; z++) s += bf2f(part[(size_t)z * stride + i]);
    float v = s * scale + (bias ? bias[i % N] : 0.0f);
    if (outF) outF[i] = v;
    else      outB[i] = f2bf(v);
}

// ---------------------------------------------------------------- rowwise LN
__device__ __forceinline__ float blockReduce(float v, float* red) {
#pragma unroll
    for (int off = 32; off > 0; off >>= 1) v += __shfl_down(v, off);
    __syncthreads();
    if ((threadIdx.x & 63) == 0) red[threadIdx.x >> 6] = v;
    __syncthreads();
    return red[0] + red[1] + red[2] + red[3];
}

__global__ __launch_bounds__(256) void k_ln_fwd(const float* __restrict__ X, int D,
    const float* __restrict__ g, const float* __restrict__ be,
    float* __restrict__ mu_out, float* __restrict__ r_out,
    u16* __restrict__ a_bf, float* __restrict__ a_f32) {
    __shared__ float red[4];
    int b = blockIdx.x, tid = threadIdx.x;
    const float* x = X + (size_t)b * D;
    int nd = D >> 8;
    float s = 0.f, s2 = 0.f;
    for (int r = 0; r < nd; r++) { float v = x[tid + (r << 8)]; s += v; s2 += v * v; }
    s = blockReduce(s, red);
    s2 = blockReduce(s2, red);
    float mu = s / D;
    float var = s2 / D - mu * mu;
    float rst = rsqrtf(var + 1e-6f);
    if (tid == 0) { mu_out[b] = mu; r_out[b] = rst; }
    for (int r = 0; r < nd; r++) {
        int i = tid + (r << 8);
        float xh = (x[i] - mu) * rst;
        float ln = xh * g[i] + be[i];
        float a = ln / (1.0f + expf(-ln));
        if (a_bf)  a_bf[(size_t)b * D + i] = f2bf(a);
        if (a_f32) a_f32[(size_t)b * D + i] = a;
    }
}

__global__ __launch_bounds__(256) void k_ln_bwd(const float* __restrict__ dup,
    const float* __restrict__ X, const float* __restrict__ mu_in, const float* __restrict__ r_in,
    const float* __restrict__ g, const float* __restrict__ be,
    u16* __restrict__ out_bf, int D) {
    __shared__ float red[4];
    int b = blockIdx.x, tid = threadIdx.x;
    const float* x = X + (size_t)b * D;
    float mu = mu_in[b], rst = r_in[b];
    int nd = D >> 8;
    float w_[4], xh_[4];
    float sw = 0.f, swx = 0.f;
    for (int r = 0; r < nd; r++) {
        int i = tid + (r << 8);
        float xh = (x[i] - mu) * rst;
        float ln = xh * g[i] + be[i];
        float sg = 1.0f / (1.0f + expf(-ln));
        float dsilu = sg * (1.0f + ln * (1.0f - sg));
        float d = dup ? dup[(size_t)b * D + i] : 1.0f;
        float w = g[i] * dsilu * d;
        w_[r] = w; xh_[r] = xh;
        sw += w; swx += w * xh;
    }
    sw = blockReduce(sw, red);
    swx = blockReduce(swx, red);
    float invD = 1.0f / D;
    for (int r = 0; r < nd; r++) {
        int i = tid + (r << 8);
        float dx = rst * (w_[r] - sw * invD - xh_[r] * swx * invD);
        out_bf[(size_t)b * D + i] = f2bf(dx);
    }
}

// ---------------------------------------------------------------- packed contraction
__global__ __launch_bounds__(256) void k_contract_p(const u16* __restrict__ Gp,
                                                    const float* __restrict__ t,
                                                    float* __restrict__ y) {
    __shared__ u16 gp_s[NPACK];
    __shared__ float xs[480];
    int b = blockIdx.x, tid = threadIdx.x;
    const uint4* gsrc = (const uint4*)(Gp + (size_t)b * NPACK);
    for (int j = tid; j < NPACK / 8; j += 256) ((uint4*)gp_s)[j] = gsrc[j];
    for (int j = tid; j < 480; j += 256) xs[j] = t[(size_t)b * 480 + j];
    __syncthreads();
    int wave = tid >> 6, lane = tid & 63;
    float* yr = y + (size_t)b * 480;
    for (int r = 0; r < 32; r++) {
        int u = wave * 32 + r;
        int v0 = lane, v1 = lane + 64;
        float s = bf2f(gp_s[pk0(u, v0)]) * xs[v0] + bf2f(gp_s[pk0(u, v1)]) * xs[v1];
#pragma unroll
        for (int off = 32; off > 0; off >>= 1) s += __shfl_down(s, off);
        if (lane == 0) yr[u] = s;
    }
    for (int r = 0; r < 16; r++) {
        int u = wave * 16 + r;
        float gv = bf2f(gp_s[pk1(u, lane)]);
        float a0 = gv * xs[128 + lane * 3 + 0];
        float a1 = gv * xs[128 + lane * 3 + 1];
        float a2 = gv * xs[128 + lane * 3 + 2];
#pragma unroll
        for (int off = 32; off > 0; off >>= 1) {
            a0 += __shfl_down(a0, off);
            a1 += __shfl_down(a1, off);
            a2 += __shfl_down(a2, off);
        }
        if (lane == 0) {
            yr[128 + u * 3 + 0] = a0;
            yr[128 + u * 3 + 1] = a1;
            yr[128 + u * 3 + 2] = a2;
        }
    }
    for (int r = 0; r < 8; r++) {
        int u = wave * 8 + r;
        bool act = lane < 32;
        float gv = act ? bf2f(gp_s[pk2(u, act ? lane : 0)]) : 0.f;
        float a[5];
#pragma unroll
        for (int m = 0; m < 5; m++)
            a[m] = act ? gv * xs[320 + lane * 5 + m] : 0.f;
#pragma unroll
        for (int off = 32; off > 0; off >>= 1)
#pragma unroll
            for (int m = 0; m < 5; m++) a[m] += __shfl_down(a[m], off);
        if (lane == 0)
#pragma unroll
            for (int m = 0; m < 5; m++) yr[320 + u * 5 + m] = a[m];
    }
}

// ---------------------------------------------------------------- launch
extern "C" void kernel_launch(void* const* d_in, const int* in_sizes, int n_in,
                              void* d_out, int out_size, void* d_ws, size_t ws_size,
                              hipStream_t stream) {
    const float* t   = (const float*)d_in[0];
    const float* w0  = (const float*)d_in[1];
    const float* w1  = (const float*)d_in[2];
    const float* w2  = (const float*)d_in[3];
    const float* W1  = (const float*)d_in[4];
    const float* b1  = (const float*)d_in[5];
    const float* g1  = (const float*)d_in[6];
    const float* be1 = (const float*)d_in[7];
    const float* W2  = (const float*)d_in[8];
    const float* b2  = (const float*)d_in[9];
    const float* g2  = (const float*)d_in[10];
    const float* be2 = (const float*)d_in[11];

    float* xout = (float*)d_out;                    // 2048*256
    float* yout = xout + (size_t)2048 * 256;        // 2048*480

    char* ws = (char*)d_ws;
    size_t off = 0;
    auto alloc = [&](size_t bytes) -> void* {
        void* p = ws + off;
        off += (bytes + 255) & ~(size_t)255;
        return p;
    };
    u16*   PG    = (u16*)alloc((size_t)2048 * NPACK * 2);   // Ppack, later Gp (aliased)
    u16*   Wsym  = (u16*)alloc((size_t)NPACK * 1024 * 2);   // packed Wsym [i,h]
    u16*   Wt    = (u16*)alloc((size_t)1024 * NPACK * 2);   // packed Wsym^T [h,i]
    u16*   uvtab = (u16*)alloc((size_t)NPACK * 2);
    u16*   W1b   = (u16*)alloc((size_t)1024 * 1024 * 2);
    u16*   W1tb  = (u16*)alloc((size_t)1024 * 1024 * 2);
    u16*   W2b   = (u16*)alloc((size_t)1024 * 256 * 2);
    u16*   W2tb  = (u16*)alloc((size_t)256 * 1024 * 2);
    u16*   h_bf  = (u16*)alloc((size_t)2048 * 1024 * 2);
    float* h1pre = (float*)alloc((size_t)2048 * 1024 * 4);
    float* mu1   = (float*)alloc(2048 * 4);
    float* r1    = (float*)alloc(2048 * 4);
    u16*   a1_bf = (u16*)alloc((size_t)2048 * 1024 * 2);
    float* h2pre = (float*)alloc((size_t)2048 * 256 * 4);
    float* mu2   = (float*)alloc(2048 * 4);
    float* r2    = (float*)alloc(2048 * 4);
    u16*   dh2b  = (u16*)alloc((size_t)2048 * 256 * 2);
    float* d_a1  = (float*)alloc((size_t)2048 * 1024 * 4);
    u16*   dh1b  = (u16*)alloc((size_t)2048 * 1024 * 2);
    u16*   de_bf = (u16*)alloc((size_t)2048 * 1024 * 2);
    u16*   Cpart = (u16*)(ws + off);
    size_t cpartBytes = (ws_size > off) ? (ws_size - off) : 0;
    (void)in_sizes; (void)n_in; (void)out_size;

    const float sF = 1.0f / sqrtf(21504.0f);

    // generic GEMM helper (MLP GEMMs): 3-D grid, optional split-K (bf16 partials)
    auto gemm = [&](const u16* A, int ldA, const u16* B, int ldB, int M, int N, int K,
                    int SKwant, float scale, const float* bias,
                    float* Cf, u16* Cb, int ldC) {
        int SK = SKwant;
        size_t slice = (size_t)M * ldC * 2;
        if (SK > 1 && cpartBytes < 2 * slice) SK = 1;
        if (SK > 1 && (size_t)SK * slice > cpartBytes) SK = (int)(cpartBytes / slice);
        while (SK > 1 && !((K % SK) == 0 && ((K / SK) % 64) == 0)) SK--;
        dim3 grid(N / 128, M / 128, SK);
        if (SK > 1) {
            k_gemm2<<<grid, 256, 0, stream>>>(A, ldA, B, ldB, K / SK, 0.f, nullptr,
                                              nullptr, nullptr, ldC, Cpart, M, 0);
            int total = M * ldC;
            k_reduce<<<(total + 255) / 256, 256, 0, stream>>>(Cpart, (size_t)M * ldC, SK,
                                                              total, N, scale, bias, Cf, Cb);
        } else {
            k_gemm2<<<grid, 256, 0, stream>>>(A, ldA, B, ldB, K, scale, bias,
                                              Cf, Cb, ldC, nullptr, M, 0);
        }
    };

    // fused prep: uv table + W transposes + W converts (one launch)
    k_prep<<<2646, 256, 0, stream>>>(uvtab, W1, W2, W1b, W1tb, W2b, W2tb);
    // packed weights (needs uvtab)
    k_packw<<<dim3(NPACK / 32, 4), 256, 0, stream>>>(w0, w1, w2, uvtab, Wsym, Wt);

    // packed features
    k_features_pack<<<2048, 256, 0, stream>>>(t, uvtab, PG);

    // GEMM1: h = sF * Ppack @ Wt^T. 256-tile: 8z x (4nT x 8mT) = 256 blocks, kLen=1408.
    k_gemm256<<<dim3(256), 512, 0, stream>>>(PG, NPACK, Wt, NPACK, NPACK / 8, 0.f, nullptr,
                                             nullptr, 1024, Cpart, 2048, 1);
    {
        int total = 2048 * 1024;
        k_reduce<<<(total + 255) / 256, 256, 0, stream>>>(Cpart, (size_t)2048 * 1024, 8,
                                                          total, 1024, sF, nullptr,
                                                          nullptr, h_bf);
    }

    // MLP forward
    gemm(h_bf, 1024, W1tb, 1024, 2048, 1024, 1024, 4, 1.0f, b1, h1pre, nullptr, 1024);
    k_ln_fwd<<<2048, 256, 0, stream>>>(h1pre, 1024, g1, be1, mu1, r1, a1_bf, nullptr);
    gemm(a1_bf, 1024, W2tb, 1024, 2048, 256, 1024, 8, 1.0f, b2, h2pre, nullptr, 256);
    k_ln_fwd<<<2048, 256, 0, stream>>>(h2pre, 256, g2, be2, mu2, r2, nullptr, xout);

    // backward
    k_ln_bwd<<<2048, 256, 0, stream>>>(nullptr, h2pre, mu2, r2, g2, be2, dh2b, 256);
    gemm(dh2b, 256, W2b, 256, 2048, 1024, 256, 4, 1.0f, nullptr, d_a1, nullptr, 1024);
    k_ln_bwd<<<2048, 256, 0, stream>>>(d_a1, h1pre, mu1, r1, g1, be1, dh1b, 1024);
    gemm(dh1b, 1024, W1b, 1024, 2048, 1024, 1024, 4, sF, nullptr, nullptr, de_bf, 1024);

    // GEMM2: Gp = de @ Wsym^T. 256-tile: 352 blocks, K=1024, XCD-local B reuse.
    u16* Gp = PG;   // Ppack dead after GEMM1
    k_gemm256<<<dim3(352), 512, 0, stream>>>(de_bf, 1024, Wsym, 1024, 1024, 1.0f, nullptr,
                                             Gp, NPACK, nullptr, 2048, 2);

    // y from packed symmetric Gp (shuffle-reduce, no atomics)
    k_contract_p<<<2048, 256, 0, stream>>>(Gp, t, yout);
}

// Round 7
// 484.295 us; speedup vs baseline: 1.1166x; 1.0347x over previous
//
#include <hip/hip_runtime.h>
#include <math.h>

typedef unsigned short u16;
typedef __bf16 bf16x8 __attribute__((ext_vector_type(8)));
typedef float f32x4 __attribute__((ext_vector_type(4)));

#define NPACK  11264   // padded packed-pair count (88*128)
#define NVALID 10864   // 8256 + 2080 + 528
#define BASE1  8256
#define BASE2  10336

__device__ __forceinline__ u16 f2bf(float f) {
    unsigned u = __builtin_bit_cast(unsigned, f);
    u += 0x7FFFu + ((u >> 16) & 1u);
    return (u16)(u >> 16);
}
__device__ __forceinline__ float bf2f(u16 h) {
    return __builtin_bit_cast(float, ((unsigned)h) << 16);
}

#define GLOAD_LDS16(g, l)                                                     \
    __builtin_amdgcn_global_load_lds(                                         \
        (const __attribute__((address_space(1))) void*)(g),                   \
        (__attribute__((address_space(3))) void*)(l), 16, 0, 0)

// packed triangular index (u<=v), per segment
__device__ __forceinline__ int pk0(int a, int b) {
    int u = min(a, b), v = max(a, b);
    return u * 128 - (u * (u - 1)) / 2 + (v - u);
}
__device__ __forceinline__ int pk1(int a, int b) {
    int u = min(a, b), v = max(a, b);
    return BASE1 + u * 64 - (u * (u - 1)) / 2 + (v - u);
}
__device__ __forceinline__ int pk2(int a, int b) {
    int u = min(a, b), v = max(a, b);
    return BASE2 + u * 32 - (u * (u - 1)) / 2 + (v - u);
}

// ---------------------------------------------------------------- fused prep
// bid <  86    : uv table
// 86..1109     : transpose W1 (32x32 tiles, grid 32x32)
// 1110..1365   : transpose W2 (grid 8x32)
// 1366..2389   : convert W1
// 2390..2645   : convert W2
__device__ __forceinline__ void prep_transpose(const float* __restrict__ in, int C,
                                               u16* __restrict__ out, int ldOut,
                                               int bx, int by, int tid) {
    __shared__ float tile[32][33];
    int tr0 = by * 32, tc0 = bx * 32;
    int lr = tid >> 5, lc = tid & 31;
#pragma unroll
    for (int i = 0; i < 4; i++) {
        int rr = lr + i * 8;
        tile[rr][lc] = in[(size_t)(tr0 + rr) * C + tc0 + lc];
    }
    __syncthreads();
#pragma unroll
    for (int i = 0; i < 4; i++) {
        int rr = lr + i * 8;
        out[(size_t)(tc0 + rr) * ldOut + tr0 + lc] = f2bf(tile[lc][rr]);
    }
}
__device__ __forceinline__ void prep_convert(const float* __restrict__ in,
                                             u16* __restrict__ out, int i, int n4) {
    if (i >= n4) return;
    float4 v = ((const float4*)in)[i];
    union { u16 a[4]; unsigned long long q; } o;
    o.a[0] = f2bf(v.x); o.a[1] = f2bf(v.y); o.a[2] = f2bf(v.z); o.a[3] = f2bf(v.w);
    ((unsigned long long*)out)[i] = o.q;
}

__global__ __launch_bounds__(256) void k_prep(u16* __restrict__ tab,
                                              const float* __restrict__ W1,
                                              const float* __restrict__ W2,
                                              u16* __restrict__ W1b,
                                              u16* __restrict__ W1tb,
                                              u16* __restrict__ W2b,
                                              u16* __restrict__ W2tb) {
    int bid = blockIdx.x, tid = threadIdx.x;
    if (bid < 86) {
        int j = bid * 256 + tid;
        if (j < 16384) {
            int u = j >> 7, v = j & 127;
            if (v >= u) tab[pk0(u, v)] = (u16)((u << 7) | v);
        } else if (j < 20480) {
            int k = j - 16384, u = k >> 6, v = k & 63;
            if (v >= u) tab[pk1(u, v)] = (u16)((1 << 14) | (u << 7) | v);
        } else if (j < 21504) {
            int k = j - 20480, u = k >> 5, v = k & 31;
            if (v >= u) tab[pk2(u, v)] = (u16)((2 << 14) | (u << 7) | v);
        } else if (j < 21504 + (NPACK - NVALID)) {
            tab[NVALID + (j - 21504)] = 0xFFFFu;
        }
    } else if (bid < 1110) {
        int k = bid - 86;                       // grid 32x32
        prep_transpose(W1, 1024, W1tb, 1024, k & 31, k >> 5, tid);
    } else if (bid < 1366) {
        int k = bid - 1110;                     // grid 8x32
        prep_transpose(W2, 256, W2tb, 1024, k & 7, k >> 3, tid);
    } else if (bid < 2390) {
        prep_convert(W1, W1b, (bid - 1366) * 256 + tid, 1024 * 1024 / 4);
    } else {
        prep_convert(W2, W2b, (bid - 2390) * 256 + tid, 1024 * 256 / 4);
    }
}

// ---------------------------------------------------------------- packed weights
__global__ __launch_bounds__(256) void k_packw(const float* __restrict__ w0,
                                               const float* __restrict__ w1,
                                               const float* __restrict__ w2,
                                               const u16* __restrict__ tab,
                                               u16* __restrict__ Wsym,
                                               u16* __restrict__ Wt) {
    __shared__ u16 tile[32][258];
    __shared__ u16 te[32];
    int i0 = blockIdx.x * 32, h0 = blockIdx.y * 256, tid = threadIdx.x;
    if (tid < 32) te[tid] = tab[i0 + tid];
    __syncthreads();
    const float s1 = 0.57735026918962576f, s2 = 0.44721359549995794f;
    for (int il = 0; il < 32; il++) {
        unsigned e = te[il];
        float val = 0.f;
        if ((e >> 14) != 3) {
            int seg = e >> 14, u = (e >> 7) & 127, v = e & 127;
            const float* wb; int S; float sc;
            if (seg == 0)      { wb = w0; S = 128; sc = 1.f; }
            else if (seg == 1) { wb = w1; S = 64;  sc = s1; }
            else               { wb = w2; S = 32;  sc = s2; }
            val = sc * (wb[(size_t)(u * S + v) * 1024 + h0 + tid] +
                        wb[(size_t)(v * S + u) * 1024 + h0 + tid]);
        }
        u16 bv = f2bf(val);
        Wsym[(size_t)(i0 + il) * 1024 + h0 + tid] = bv;
        tile[il][tid] = bv;
    }
    __syncthreads();
    union { u16 a[32]; uint4 q[4]; } pk;
#pragma unroll
    for (int il = 0; il < 32; il++) pk.a[il] = tile[il][tid];
    uint4* dst = (uint4*)(Wt + (size_t)(h0 + tid) * NPACK + i0);
#pragma unroll
    for (int q = 0; q < 4; q++) dst[q] = pk.q[q];
}

// ---------------------------------------------------------------- packed features
__global__ __launch_bounds__(256) void k_features_pack(const float* __restrict__ t,
                                                       const u16* __restrict__ tab,
                                                       u16* __restrict__ P) {
    __shared__ u16 tab_s[NPACK];
    __shared__ float tr[480];
    int b = blockIdx.x, tid = threadIdx.x;
    for (int j = tid; j < NPACK / 8; j += 256)
        ((uint4*)tab_s)[j] = ((const uint4*)tab)[j];
    for (int j = tid; j < 480; j += 256) tr[j] = t[(size_t)b * 480 + j];
    __syncthreads();
    u16* row = P + (size_t)b * NPACK;
    for (int i = tid; i < NPACK; i += 256) {
        unsigned e = tab_s[i];
        float p = 0.f;
        if ((e >> 14) != 3) {
            int seg = e >> 14, u = (e >> 7) & 127, v = e & 127;
            if (seg == 0) p = tr[u] * tr[v];
            else if (seg == 1) {
                const float* x1 = tr + 128;
                p = x1[u*3]*x1[v*3] + x1[u*3+1]*x1[v*3+1] + x1[u*3+2]*x1[v*3+2];
            } else {
                const float* x2 = tr + 320;
#pragma unroll
                for (int m = 0; m < 5; m++) p += x2[u*5+m] * x2[v*5+m];
            }
            if (u == v) p *= 0.5f;
        }
        row[i] = f2bf(p);
    }
}

// ---------------------------------------------------------------- GEMM 128-tile (MLP sizes)
__global__ __launch_bounds__(256) void k_gemm2(const u16* __restrict__ A, int ldA,
                                               const u16* __restrict__ B, int ldB,
                                               int kLen, float scale,
                                               const float* __restrict__ bias,
                                               float* __restrict__ Cf,
                                               u16* __restrict__ Cb, int ldC,
                                               u16* __restrict__ Cpart, int Mtot,
                                               int swz) {
    __shared__ u16 As[2][128 * 32];
    __shared__ u16 Bs[2][128 * 32];
    const int tid = threadIdx.x;
    const int wave = tid >> 6, lane = tid & 63;
    const int wm = wave >> 1, wn = wave & 1;
    int nT, mT, z;
    if (swz == 1) {
        int L = blockIdx.x;
        z = L & 7; int r = L >> 3;
        nT = r >> 4; mT = r & 15;
    } else if (swz == 2) {
        int L = blockIdx.x;
        int c = L & 7, r = L >> 3;
        nT = (r % 11) * 8 + c; mT = r / 11; z = 0;
    } else {
        nT = blockIdx.x; mT = blockIdx.y; z = blockIdx.z;
    }
    const int m0 = mT * 128, n0 = nT * 128;
    const size_t kOff = (size_t)z * kLen;

    const int chl = (((lane & 3) ^ ((lane >> 3) & 3))) * 8;
    const u16* aG = A + (size_t)(m0 + wave * 32 + (lane >> 2)) * ldA + kOff + chl;
    const u16* bG = B + (size_t)(n0 + wave * 32 + (lane >> 2)) * ldB + kOff + chl;
    const size_t aS = (size_t)16 * ldA;
    const size_t bS = (size_t)16 * ldB;
    u16* aL0 = &As[0][(wave * 32) * 32];
    u16* aL1 = &As[0][(wave * 32 + 16) * 32];
    u16* aH0 = &As[1][(wave * 32) * 32];
    u16* aH1 = &As[1][(wave * 32 + 16) * 32];
    u16* bL0 = &Bs[0][(wave * 32) * 32];
    u16* bL1 = &Bs[0][(wave * 32 + 16) * 32];
    u16* bH0 = &Bs[1][(wave * 32) * 32];
    u16* bH1 = &Bs[1][(wave * 32 + 16) * 32];

    f32x4 acc[4][4];
#pragma unroll
    for (int i = 0; i < 4; i++)
#pragma unroll
        for (int j = 0; j < 4; j++) acc[i][j] = (f32x4){0.f, 0.f, 0.f, 0.f};

    const int ml = lane & 15, kq8 = lane >> 4;
    const int kqs = (kq8 ^ ((ml >> 1) & 3)) * 8;
    const u16* aRd0 = &As[0][(wm * 64 + ml) * 32 + kqs];
    const u16* bRd0 = &Bs[0][(wn * 64 + ml) * 32 + kqs];
    const u16* aRd1 = &As[1][(wm * 64 + ml) * 32 + kqs];
    const u16* bRd1 = &Bs[1][(wn * 64 + ml) * 32 + kqs];

    for (int k = 0; k < kLen; k += 64) {
        GLOAD_LDS16(aG, aL0);
        GLOAD_LDS16(aG + aS, aL1);
        GLOAD_LDS16(aG + 32, aH0);
        GLOAD_LDS16(aG + aS + 32, aH1);
        GLOAD_LDS16(bG, bL0);
        GLOAD_LDS16(bG + bS, bL1);
        GLOAD_LDS16(bG + 32, bH0);
        GLOAD_LDS16(bG + bS + 32, bH1);
        aG += 64; bG += 64;
        __syncthreads();
        {
            bf16x8 af[4], bfv[4];
#pragma unroll
            for (int i = 0; i < 4; i++) af[i]  = *(const bf16x8*)(aRd0 + i * 16 * 32);
#pragma unroll
            for (int j = 0; j < 4; j++) bfv[j] = *(const bf16x8*)(bRd0 + j * 16 * 32);
#pragma unroll
            for (int i = 0; i < 4; i++)
#pragma unroll
                for (int j = 0; j < 4; j++)
                    acc[i][j] = __builtin_amdgcn_mfma_f32_16x16x32_bf16(af[i], bfv[j], acc[i][j], 0, 0, 0);
        }
        {
            bf16x8 af[4], bfv[4];
#pragma unroll
            for (int i = 0; i < 4; i++) af[i]  = *(const bf16x8*)(aRd1 + i * 16 * 32);
#pragma unroll
            for (int j = 0; j < 4; j++) bfv[j] = *(const bf16x8*)(bRd1 + j * 16 * 32);
#pragma unroll
            for (int i = 0; i < 4; i++)
#pragma unroll
                for (int j = 0; j < 4; j++)
                    acc[i][j] = __builtin_amdgcn_mfma_f32_16x16x32_bf16(af[i], bfv[j], acc[i][j], 0, 0, 0);
        }
        __syncthreads();
    }

    const int q = lane >> 4, nl = lane & 15;
    if (Cpart) {
        u16* outP = Cpart + (size_t)z * Mtot * ldC;
#pragma unroll
        for (int i = 0; i < 4; i++)
#pragma unroll
            for (int j = 0; j < 4; j++)
#pragma unroll
                for (int reg = 0; reg < 4; reg++) {
                    int row = m0 + wm * 64 + i * 16 + q * 4 + reg;
                    int col = n0 + wn * 64 + j * 16 + nl;
                    outP[(size_t)row * ldC + col] = f2bf(acc[i][j][reg]);
                }
    } else {
#pragma unroll
        for (int i = 0; i < 4; i++)
#pragma unroll
            for (int j = 0; j < 4; j++)
#pragma unroll
                for (int reg = 0; reg < 4; reg++) {
                    int row = m0 + wm * 64 + i * 16 + q * 4 + reg;
                    int col = n0 + wn * 64 + j * 16 + nl;
                    float v = acc[i][j][reg] * scale + (bias ? bias[col] : 0.0f);
                    if (Cf) Cf[(size_t)row * ldC + col] = v;
                    else    Cb[(size_t)row * ldC + col] = f2bf(v);
                }
    }
}

// ---------------------------------------------------------------- GEMM 256-tile (GEMM1), R3 schedule
#define VMCNT0 asm volatile("s_waitcnt vmcnt(0)" ::: "memory")
#define BARX() __builtin_amdgcn_s_barrier()

#define STG_A(p, kh, rh, kb) GLOAD_LDS16(aB + (size_t)(rh) * aH + (kb) + (kh) * 32, \
                                         &As[p][kh][((rh) * 128 + wave * 16) * 32])
#define STG_B(p, kh, rh, kb) GLOAD_LDS16(bB + (size_t)(rh) * bH + (kb) + (kh) * 32, \
                                         &Bs[p][kh][((rh) * 128 + wave * 16) * 32])
#define MMQ(fb, gb, bv) do { _Pragma("unroll") \
    for (int ff = 0; ff < 4; ff++) { _Pragma("unroll") \
        for (int gg = 0; gg < 2; gg++) { \
            acc[(fb)+ff][(gb)+gg] = __builtin_amdgcn_mfma_f32_16x16x32_bf16(a[2*ff],   bv[2*gg],   acc[(fb)+ff][(gb)+gg], 0, 0, 0); \
            acc[(fb)+ff][(gb)+gg] = __builtin_amdgcn_mfma_f32_16x16x32_bf16(a[2*ff+1], bv[2*gg+1], acc[(fb)+ff][(gb)+gg], 0, 0, 0); } } } while (0)

__global__ __launch_bounds__(512, 2) void k_gemm256(const u16* __restrict__ A, int ldA,
                                                    const u16* __restrict__ B, int ldB,
                                                    int kLen, float scale,
                                                    const float* __restrict__ bias,
                                                    u16* __restrict__ Cb, int ldC,
                                                    u16* __restrict__ Cpart, int Mtot,
                                                    int swz) {
    __shared__ __align__(16) u16 As[2][2][256 * 32];   // [buf][kh][row*32+k]  64 KB
    __shared__ __align__(16) u16 Bs[2][2][256 * 32];   // 64 KB
    const int tid = threadIdx.x;
    const int lane = tid & 63, wave = tid >> 6;
    const int wm = wave >> 2, wn = wave & 3;
    int mT, nT, z;
    if (swz == 1) {
        // GEMM1: 256 blocks. XCD = z = L&7. Within XCD: nT fastest.
        z = blockIdx.x & 7; int r = blockIdx.x >> 3; nT = r & 3; mT = r >> 2;
    } else {
        int x = blockIdx.x & 7, j = blockIdx.x >> 3;
        int nti = j >> 3; mT = j & 7;
        if (nti < 5)      nT = nti * 8 + x;
        else if (x < 4)   nT = 40 + x;
        else            { nT = 40 + (x - 4); mT = (j & 7) + 4; }
        z = 0;
    }
    const int m0 = mT * 256, n0 = nT * 256;
    const size_t kOff = (size_t)z * kLen;
    const int nTi = kLen >> 6;          // K-64 tiles, >= 2

    const int chl = ((tid & 3) ^ ((tid >> 3) & 3)) * 8;
    const u16* aB = A + (size_t)(m0 + (tid >> 2)) * ldA + kOff + chl;
    const u16* bB = B + (size_t)(n0 + (tid >> 2)) * ldB + kOff + chl;
    const size_t aH = (size_t)128 * ldA;
    const size_t bH = (size_t)128 * ldB;

    const int ml = lane & 15, kq8 = lane >> 4;
    const int kqs = (kq8 ^ ((ml >> 1) & 3)) * 8;
    const int aro = (wm * 128 + ml) * 32 + kqs;
    const int bro = (wn * 64 + ml) * 32 + kqs;

    f32x4 acc[8][4];
#pragma unroll
    for (int f = 0; f < 8; f++)
#pragma unroll
        for (int g = 0; g < 4; g++) acc[f][g] = (f32x4){0.f, 0.f, 0.f, 0.f};
    bf16x8 a[8], b[4], b2[4];

    STG_A(0, 0, 0, 0); STG_A(0, 0, 1, 0); STG_A(0, 1, 0, 0); STG_A(0, 1, 1, 0);
    STG_B(0, 0, 0, 0); STG_B(0, 0, 1, 0); STG_B(0, 1, 0, 0); STG_B(0, 1, 1, 0);
    VMCNT0;
    BARX();

    for (int t = 0; t < nTi; t++) {
        const int p = t & 1, p1 = p ^ 1;
        const int kb1 = (t + 1) << 6;
        const bool s1 = (t + 1) < nTi;
        // phase 0
#pragma unroll
        for (int f = 0; f < 4; f++) {
            a[2*f]   = *(const bf16x8*)&As[p][0][aro + f * 512];
            a[2*f+1] = *(const bf16x8*)&As[p][1][aro + f * 512];
        }
#pragma unroll
        for (int g = 0; g < 2; g++) {
            b[2*g]   = *(const bf16x8*)&Bs[p][0][bro + g * 512];
            b[2*g+1] = *(const bf16x8*)&Bs[p][1][bro + g * 512];
        }
        if (s1) { STG_A(p1, 0, 0, kb1); STG_A(p1, 0, 1, kb1); }
        BARX();
        __builtin_amdgcn_s_setprio(1);
        MMQ(0, 0, b);
        __builtin_amdgcn_s_setprio(0);
        BARX();
        // phase 1
#pragma unroll
        for (int g = 0; g < 2; g++) {
            b2[2*g]   = *(const bf16x8*)&Bs[p][0][bro + (g + 2) * 512];
            b2[2*g+1] = *(const bf16x8*)&Bs[p][1][bro + (g + 2) * 512];
        }
        if (s1) { STG_A(p1, 1, 0, kb1); STG_A(p1, 1, 1, kb1); }
        BARX();
        __builtin_amdgcn_s_setprio(1);
        MMQ(0, 2, b2);
        __builtin_amdgcn_s_setprio(0);
        BARX();
        // phase 2
#pragma unroll
        for (int f = 0; f < 4; f++) {
            a[2*f]   = *(const bf16x8*)&As[p][0][aro + (f + 4) * 512];
            a[2*f+1] = *(const bf16x8*)&As[p][1][aro + (f + 4) * 512];
        }
        if (s1) { STG_B(p1, 0, 0, kb1); STG_B(p1, 0, 1, kb1); }
        BARX();
        __builtin_amdgcn_s_setprio(1);
        MMQ(4, 0, b);
        __builtin_amdgcn_s_setprio(0);
        BARX();
        // phase 3
        if (s1) { STG_B(p1, 1, 0, kb1); STG_B(p1, 1, 1, kb1); }
        __builtin_amdgcn_s_setprio(1);
        MMQ(4, 2, b2);
        __builtin_amdgcn_s_setprio(0);
        if (s1) VMCNT0;
        BARX();
    }

    const int q = lane >> 4, nl = lane & 15;
    if (Cpart) {
        u16* outP = Cpart + (size_t)z * Mtot * ldC;
#pragma unroll
        for (int f = 0; f < 8; f++)
#pragma unroll
            for (int g = 0; g < 4; g++)
#pragma unroll
                for (int reg = 0; reg < 4; reg++) {
                    int row = m0 + wm * 128 + f * 16 + q * 4 + reg;
                    int col = n0 + wn * 64 + g * 16 + nl;
                    outP[(size_t)row * ldC + col] = f2bf(acc[f][g][reg]);
                }
    } else {
#pragma unroll
        for (int f = 0; f < 8; f++)
#pragma unroll
            for (int g = 0; g < 4; g++)
#pragma unroll
                for (int reg = 0; reg < 4; reg++) {
                    int row = m0 + wm * 128 + f * 16 + q * 4 + reg;
                    int col = n0 + wn * 64 + g * 16 + nl;
                    float v = acc[f][g][reg] * scale + (bias ? bias[col] : 0.0f);
                    Cb[(size_t)row * ldC + col] = f2bf(v);
                }
    }
}

// ---------------------------------------------------------------- GEMM 128x256-tile (GEMM2)
// Same R3 phase schedule, halved M-tile: 8 waves, per-wave 64x64 output
// (wm=wave>>2 in 0..1, wn=wave&3). LDS 96 KB (A 32 KB + B 64 KB). 6 staging
// loads/tile (A kh0,kh1 = 1 each; B kh x rh = 4) issued 2/2/2/0 across phases.
// 704 blocks -> ~2.75 balanced rounds on 256 CUs (fixes GEMM2's 2-round
// imbalance at 352x256^2); per-wave LDS read volume/output -33% (less dup).
#define MMQ22(fb, gb, bv) do { _Pragma("unroll") \
    for (int ff = 0; ff < 2; ff++) { _Pragma("unroll") \
        for (int gg = 0; gg < 2; gg++) { \
            acc[(fb)+ff][(gb)+gg] = __builtin_amdgcn_mfma_f32_16x16x32_bf16(a[2*ff],   bv[2*gg],   acc[(fb)+ff][(gb)+gg], 0, 0, 0); \
            acc[(fb)+ff][(gb)+gg] = __builtin_amdgcn_mfma_f32_16x16x32_bf16(a[2*ff+1], bv[2*gg+1], acc[(fb)+ff][(gb)+gg], 0, 0, 0); } } } while (0)

__global__ __launch_bounds__(512, 2) void k_gemm128n(const u16* __restrict__ A, int ldA,
                                                     const u16* __restrict__ B, int ldB,
                                                     int kLen, float scale,
                                                     u16* __restrict__ Cb, int ldC) {
    __shared__ __align__(16) u16 As[2][2][128 * 32];   // [buf][kh] 32 KB total
    __shared__ __align__(16) u16 Bs[2][2][256 * 32];   // 64 KB
    const int tid = threadIdx.x;
    const int lane = tid & 63, wave = tid >> 6;
    const int wm = wave >> 2, wn = wave & 3;           // wm 0..1, wn 0..3
    // 704 blocks: x = XCD, j = L>>3 in 0..87; nti = j>>4, mT = j&15 (16 M-tiles).
    // nti<5: nT = nti*8+x (B-panel 0.5MB reused 16x consecutive per XCD).
    // tail (nti=5, j&15 in 0..7): nT = 40+(x&3), mT = (j&7) + 8*(x>>2).
    int x = blockIdx.x & 7, j = blockIdx.x >> 3;
    int nti = j >> 4, mT = j & 15, nT;
    if (nti < 5) nT = nti * 8 + x;
    else { nT = 40 + (x & 3); mT = (j & 7) + 8 * (x >> 2); }
    const int m0 = mT * 128, n0 = nT * 256;
    const int nTi = kLen >> 6;

    const int chl = ((tid & 3) ^ ((tid >> 3) & 3)) * 8;
    const u16* aB = A + (size_t)(m0 + (tid >> 2)) * ldA + chl;   // rows 0..127
    const u16* bB = B + (size_t)(n0 + (tid >> 2)) * ldB + chl;
    const size_t bH = (size_t)128 * ldB;

    const int ml = lane & 15, kq8 = lane >> 4;
    const int kqs = (kq8 ^ ((ml >> 1) & 3)) * 8;
    const int aro = (wm * 64 + ml) * 32 + kqs;
    const int bro = (wn * 64 + ml) * 32 + kqs;

    f32x4 acc[4][4];
#pragma unroll
    for (int f = 0; f < 4; f++)
#pragma unroll
        for (int g = 0; g < 4; g++) acc[f][g] = (f32x4){0.f, 0.f, 0.f, 0.f};
    bf16x8 a[4], b[4], b2[4];

#define SG_A(p, kh, kb) GLOAD_LDS16(aB + (kb) + (kh) * 32, &As[p][kh][(wave * 16) * 32])
#define SG_B(p, kh, rh, kb) GLOAD_LDS16(bB + (size_t)(rh) * bH + (kb) + (kh) * 32, \
                                        &Bs[p][kh][((rh) * 128 + wave * 16) * 32])

    // prologue: tile 0 (6 loads), drain, barrier
    SG_A(0, 0, 0); SG_A(0, 1, 0);
    SG_B(0, 0, 0, 0); SG_B(0, 0, 1, 0); SG_B(0, 1, 0, 0); SG_B(0, 1, 1, 0);
    VMCNT0;
    BARX();

    for (int t = 0; t < nTi; t++) {
        const int p = t & 1, p1 = p ^ 1;
        const int kb1 = (t + 1) << 6;
        const bool s1 = (t + 1) < nTi;
        // phase 0: a f0..1, b g0..1; stage t+1 A kh0+kh1
#pragma unroll
        for (int f = 0; f < 2; f++) {
            a[2*f]   = *(const bf16x8*)&As[p][0][aro + f * 512];
            a[2*f+1] = *(const bf16x8*)&As[p][1][aro + f * 512];
        }
#pragma unroll
        for (int g = 0; g < 2; g++) {
            b[2*g]   = *(const bf16x8*)&Bs[p][0][bro + g * 512];
            b[2*g+1] = *(const bf16x8*)&Bs[p][1][bro + g * 512];
        }
        if (s1) { SG_A(p1, 0, kb1); SG_A(p1, 1, kb1); }
        BARX();
        __builtin_amdgcn_s_setprio(1);
        MMQ22(0, 0, b);
        __builtin_amdgcn_s_setprio(0);
        BARX();
        // phase 1: b2 g2..3; stage t+1 B kh0
#pragma unroll
        for (int g = 0; g < 2; g++) {
            b2[2*g]   = *(const bf16x8*)&Bs[p][0][bro + (g + 2) * 512];
            b2[2*g+1] = *(const bf16x8*)&Bs[p][1][bro + (g + 2) * 512];
        }
        if (s1) { SG_B(p1, 0, 0, kb1); SG_B(p1, 0, 1, kb1); }
        BARX();
        __builtin_amdgcn_s_setprio(1);
        MMQ22(0, 2, b2);
        __builtin_amdgcn_s_setprio(0);
        BARX();
        // phase 2: a f2..3; stage t+1 B kh1
#pragma unroll
        for (int f = 0; f < 2; f++) {
            a[2*f]   = *(const bf16x8*)&As[p][0][aro + (f + 2) * 512];
            a[2*f+1] = *(const bf16x8*)&As[p][1][aro + (f + 2) * 512];
        }
        if (s1) { SG_B(p1, 1, 0, kb1); SG_B(p1, 1, 1, kb1); }
        BARX();
        __builtin_amdgcn_s_setprio(1);
        MMQ22(2, 0, b);
        __builtin_amdgcn_s_setprio(0);
        BARX();
        // phase 3: no reads/stages; tile-boundary drain
        __builtin_amdgcn_s_setprio(1);
        MMQ22(2, 2, b2);
        __builtin_amdgcn_s_setprio(0);
        if (s1) VMCNT0;
        BARX();
    }

    const int q = lane >> 4, nl = lane & 15;
#pragma unroll
    for (int f = 0; f < 4; f++)
#pragma unroll
        for (int g = 0; g < 4; g++)
#pragma unroll
            for (int reg = 0; reg < 4; reg++) {
                int row = m0 + wm * 64 + f * 16 + q * 4 + reg;
                int col = n0 + wn * 64 + g * 16 + nl;
                Cb[(size_t)row * ldC + col] = f2bf(acc[f][g][reg] * scale);
            }
}

// sum split-K bf16 partials + epilogue
__global__ __launch_bounds__(256) void k_reduce(const u16* __restrict__ part, size_t stride,
                                                int SK, int total, int N, float scale,
                                                const float* __restrict__ bias,
                                                float* __restrict__ outF, u16* __restrict__ outB) {
    int i = blockIdx.x * 256 + threadIdx.x;
    if (i >= total) return;
    float s = 0.f;
    for (int z = 0; z < SK; z++) s += bf2f(part[(size_t)z * stride + i]);
    float v = s * scale + (bias ? bias[i % N] : 0.0f);
    if (outF) outF[i] = v;
    else      outB[i] = f2bf(v);
}

// ---------------------------------------------------------------- rowwise LN
__device__ __forceinline__ float blockReduce(float v, float* red) {
#pragma unroll
    for (int off = 32; off > 0; off >>= 1) v += __shfl_down(v, off);
    __syncthreads();
    if ((threadIdx.x & 63) == 0) red[threadIdx.x >> 6] = v;
    __syncthreads();
    return red[0] + red[1] + red[2] + red[3];
}

__global__ __launch_bounds__(256) void k_ln_fwd(const float* __restrict__ X, int D,
    const float* __restrict__ g, const float* __restrict__ be,
    float* __restrict__ mu_out, float* __restrict__ r_out,
    u16* __restrict__ a_bf, float* __restrict__ a_f32) {
    __shared__ float red[4];
    int b = blockIdx.x, tid = threadIdx.x;
    const float* x = X + (size_t)b * D;
    int nd = D >> 8;
    float s = 0.f, s2 = 0.f;
    for (int r = 0; r < nd; r++) { float v = x[tid + (r << 8)]; s += v; s2 += v * v; }
    s = blockReduce(s, red);
    s2 = blockReduce(s2, red);
    float mu = s / D;
    float var = s2 / D - mu * mu;
    float rst = rsqrtf(var + 1e-6f);
    if (tid == 0) { mu_out[b] = mu; r_out[b] = rst; }
    for (int r = 0; r < nd; r++) {
        int i = tid + (r << 8);
        float xh = (x[i] - mu) * rst;
        float ln = xh * g[i] + be[i];
        float a = ln / (1.0f + expf(-ln));
        if (a_bf)  a_bf[(size_t)b * D + i] = f2bf(a);
        if (a_f32) a_f32[(size_t)b * D + i] = a;
    }
}

__global__ __launch_bounds__(256) void k_ln_bwd(const float* __restrict__ dup,
    const float* __restrict__ X, const float* __restrict__ mu_in, const float* __restrict__ r_in,
    const float* __restrict__ g, const float* __restrict__ be,
    u16* __restrict__ out_bf, int D) {
    __shared__ float red[4];
    int b = blockIdx.x, tid = threadIdx.x;
    const float* x = X + (size_t)b * D;
    float mu = mu_in[b], rst = r_in[b];
    int nd = D >> 8;
    float w_[4], xh_[4];
    float sw = 0.f, swx = 0.f;
    for (int r = 0; r < nd; r++) {
        int i = tid + (r << 8);
        float xh = (x[i] - mu) * rst;
        float ln = xh * g[i] + be[i];
        float sg = 1.0f / (1.0f + expf(-ln));
        float dsilu = sg * (1.0f + ln * (1.0f - sg));
        float d = dup ? dup[(size_t)b * D + i] : 1.0f;
        float w = g[i] * dsilu * d;
        w_[r] = w; xh_[r] = xh;
        sw += w; swx += w * xh;
    }
    sw = blockReduce(sw, red);
    swx = blockReduce(swx, red);
    float invD = 1.0f / D;
    for (int r = 0; r < nd; r++) {
        int i = tid + (r << 8);
        float dx = rst * (w_[r] - sw * invD - xh_[r] * swx * invD);
        out_bf[(size_t)b * D + i] = f2bf(dx);
    }
}

// ---------------------------------------------------------------- packed contraction
__global__ __launch_bounds__(256) void k_contract_p(const u16* __restrict__ Gp,
                                                    const float* __restrict__ t,
                                                    float* __restrict__ y) {
    __shared__ u16 gp_s[NPACK];
    __shared__ float xs[480];
    int b = blockIdx.x, tid = threadIdx.x;
    const uint4* gsrc = (const uint4*)(Gp + (size_t)b * NPACK);
    for (int j = tid; j < NPACK / 8; j += 256) ((uint4*)gp_s)[j] = gsrc[j];
    for (int j = tid; j < 480; j += 256) xs[j] = t[(size_t)b * 480 + j];
    __syncthreads();
    int wave = tid >> 6, lane = tid & 63;
    float* yr = y + (size_t)b * 480;
    for (int r = 0; r < 32; r++) {
        int u = wave * 32 + r;
        int v0 = lane, v1 = lane + 64;
        float s = bf2f(gp_s[pk0(u, v0)]) * xs[v0] + bf2f(gp_s[pk0(u, v1)]) * xs[v1];
#pragma unroll
        for (int off = 32; off > 0; off >>= 1) s += __shfl_down(s, off);
        if (lane == 0) yr[u] = s;
    }
    for (int r = 0; r < 16; r++) {
        int u = wave * 16 + r;
        float gv = bf2f(gp_s[pk1(u, lane)]);
        float a0 = gv * xs[128 + lane * 3 + 0];
        float a1 = gv * xs[128 + lane * 3 + 1];
        float a2 = gv * xs[128 + lane * 3 + 2];
#pragma unroll
        for (int off = 32; off > 0; off >>= 1) {
            a0 += __shfl_down(a0, off);
            a1 += __shfl_down(a1, off);
            a2 += __shfl_down(a2, off);
        }
        if (lane == 0) {
            yr[128 + u * 3 + 0] = a0;
            yr[128 + u * 3 + 1] = a1;
            yr[128 + u * 3 + 2] = a2;
        }
    }
    for (int r = 0; r < 8; r++) {
        int u = wave * 8 + r;
        bool act = lane < 32;
        float gv = act ? bf2f(gp_s[pk2(u, act ? lane : 0)]) : 0.f;
        float a[5];
#pragma unroll
        for (int m = 0; m < 5; m++)
            a[m] = act ? gv * xs[320 + lane * 5 + m] : 0.f;
#pragma unroll
        for (int off = 32; off > 0; off >>= 1)
#pragma unroll
            for (int m = 0; m < 5; m++) a[m] += __shfl_down(a[m], off);
        if (lane == 0)
#pragma unroll
            for (int m = 0; m < 5; m++) yr[320 + u * 5 + m] = a[m];
    }
}

// ---------------------------------------------------------------- launch
extern "C" void kernel_launch(void* const* d_in, const int* in_sizes, int n_in,
                              void* d_out, int out_size, void* d_ws, size_t ws_size,
                              hipStream_t stream) {
    const float* t   = (const float*)d_in[0];
    const float* w0  = (const float*)d_in[1];
    const float* w1  = (const float*)d_in[2];
    const float* w2  = (const float*)d_in[3];
    const float* W1  = (const float*)d_in[4];
    const float* b1  = (const float*)d_in[5];
    const float* g1  = (const float*)d_in[6];
    const float* be1 = (const float*)d_in[7];
    const float* W2  = (const float*)d_in[8];
    const float* b2  = (const float*)d_in[9];
    const float* g2  = (const float*)d_in[10];
    const float* be2 = (const float*)d_in[11];

    float* xout = (float*)d_out;                    // 2048*256
    float* yout = xout + (size_t)2048 * 256;        // 2048*480

    char* ws = (char*)d_ws;
    size_t off = 0;
    auto alloc = [&](size_t bytes) -> void* {
        void* p = ws + off;
        off += (bytes + 255) & ~(size_t)255;
        return p;
    };
    u16*   PG    = (u16*)alloc((size_t)2048 * NPACK * 2);   // Ppack, later Gp (aliased)
    u16*   Wsym  = (u16*)alloc((size_t)NPACK * 1024 * 2);   // packed Wsym [i,h]
    u16*   Wt    = (u16*)alloc((size_t)1024 * NPACK * 2);   // packed Wsym^T [h,i]
    u16*   uvtab = (u16*)alloc((size_t)NPACK * 2);
    u16*   W1b   = (u16*)alloc((size_t)1024 * 1024 * 2);
    u16*   W1tb  = (u16*)alloc((size_t)1024 * 1024 * 2);
    u16*   W2b   = (u16*)alloc((size_t)1024 * 256 * 2);
    u16*   W2tb  = (u16*)alloc((size_t)256 * 1024 * 2);
    u16*   h_bf  = (u16*)alloc((size_t)2048 * 1024 * 2);
    float* h1pre = (float*)alloc((size_t)2048 * 1024 * 4);
    float* mu1   = (float*)alloc(2048 * 4);
    float* r1    = (float*)alloc(2048 * 4);
    u16*   a1_bf = (u16*)alloc((size_t)2048 * 1024 * 2);
    float* h2pre = (float*)alloc((size_t)2048 * 256 * 4);
    float* mu2   = (float*)alloc(2048 * 4);
    float* r2    = (float*)alloc(2048 * 4);
    u16*   dh2b  = (u16*)alloc((size_t)2048 * 256 * 2);
    float* d_a1  = (float*)alloc((size_t)2048 * 1024 * 4);
    u16*   dh1b  = (u16*)alloc((size_t)2048 * 1024 * 2);
    u16*   de_bf = (u16*)alloc((size_t)2048 * 1024 * 2);
    u16*   Cpart = (u16*)(ws + off);
    size_t cpartBytes = (ws_size > off) ? (ws_size - off) : 0;
    (void)in_sizes; (void)n_in; (void)out_size;

    const float sF = 1.0f / sqrtf(21504.0f);

    // generic GEMM helper (MLP GEMMs): 3-D grid, optional split-K (bf16 partials)
    auto gemm = [&](const u16* A, int ldA, const u16* B, int ldB, int M, int N, int K,
                    int SKwant, float scale, const float* bias,
                    float* Cf, u16* Cb, int ldC) {
        int SK = SKwant;
        size_t slice = (size_t)M * ldC * 2;
        if (SK > 1 && cpartBytes < 2 * slice) SK = 1;
        if (SK > 1 && (size_t)SK * slice > cpartBytes) SK = (int)(cpartBytes / slice);
        while (SK > 1 && !((K % SK) == 0 && ((K / SK) % 64) == 0)) SK--;
        dim3 grid(N / 128, M / 128, SK);
        if (SK > 1) {
            k_gemm2<<<grid, 256, 0, stream>>>(A, ldA, B, ldB, K / SK, 0.f, nullptr,
                                              nullptr, nullptr, ldC, Cpart, M, 0);
            int total = M * ldC;
            k_reduce<<<(total + 255) / 256, 256, 0, stream>>>(Cpart, (size_t)M * ldC, SK,
                                                              total, N, scale, bias, Cf, Cb);
        } else {
            k_gemm2<<<grid, 256, 0, stream>>>(A, ldA, B, ldB, K, scale, bias,
                                              Cf, Cb, ldC, nullptr, M, 0);
        }
    };

    // fused prep: uv table + W transposes + W converts (one launch)
    k_prep<<<2646, 256, 0, stream>>>(uvtab, W1, W2, W1b, W1tb, W2b, W2tb);
    // packed weights (needs uvtab)
    k_packw<<<dim3(NPACK / 32, 4), 256, 0, stream>>>(w0, w1, w2, uvtab, Wsym, Wt);

    // packed features
    k_features_pack<<<2048, 256, 0, stream>>>(t, uvtab, PG);

    // GEMM1: h = sF * Ppack @ Wt^T. 256-tile: 8z x (4nT x 8mT) = 256 blocks, kLen=1408.
    k_gemm256<<<dim3(256), 512, 0, stream>>>(PG, NPACK, Wt, NPACK, NPACK / 8, 0.f, nullptr,
                                             nullptr, 1024, Cpart, 2048, 1);
    {
        int total = 2048 * 1024;
        k_reduce<<<(total + 255) / 256, 256, 0, stream>>>(Cpart, (size_t)2048 * 1024, 8,
                                                          total, 1024, sF, nullptr,
                                                          nullptr, h_bf);
    }

    // MLP forward
    gemm(h_bf, 1024, W1tb, 1024, 2048, 1024, 1024, 4, 1.0f, b1, h1pre, nullptr, 1024);
    k_ln_fwd<<<2048, 256, 0, stream>>>(h1pre, 1024, g1, be1, mu1, r1, a1_bf, nullptr);
    gemm(a1_bf, 1024, W2tb, 1024, 2048, 256, 1024, 8, 1.0f, b2, h2pre, nullptr, 256);
    k_ln_fwd<<<2048, 256, 0, stream>>>(h2pre, 256, g2, be2, mu2, r2, nullptr, xout);

    // backward
    k_ln_bwd<<<2048, 256, 0, stream>>>(nullptr, h2pre, mu2, r2, g2, be2, dh2b, 256);
    gemm(dh2b, 256, W2b, 256, 2048, 1024, 256, 4, 1.0f, nullptr, d_a1, nullptr, 1024);
    k_ln_bwd<<<2048, 256, 0, stream>>>(d_a1, h1pre, mu1, r1, g1, be1, dh1b, 1024);
    gemm(dh1b, 1024, W1b, 1024, 2048, 1024, 1024, 4, sF, nullptr, nullptr, de_bf, 1024);

    // GEMM2: Gp = de @ Wsym^T. 128x256-tile: 704 blocks (~2.75 balanced rounds).
    u16* Gp = PG;   // Ppack dead after GEMM1
    k_gemm128n<<<dim3(704), 512, 0, stream>>>(de_bf, 1024, Wsym, 1024, 1024, 1.0f,
                                              Gp, NPACK);

    // y from packed symmetric Gp (shuffle-reduce, no atomics)
    k_contract_p<<<2048, 256, 0, stream>>>(Gp, t, yout);
}

// Round 8
// 433.688 us; speedup vs baseline: 1.2469x; 1.1167x over previous
//
#include <hip/hip_runtime.h>
#include <math.h>

typedef unsigned short u16;
typedef __bf16 bf16x8 __attribute__((ext_vector_type(8)));
typedef float f32x4 __attribute__((ext_vector_type(4)));

#define NPACK  11264   // padded packed-pair count (88*128)
#define NVALID 10864   // 8256 + 2080 + 528
#define BASE1  8256
#define BASE2  10336

__device__ __forceinline__ u16 f2bf(float f) {
    unsigned u = __builtin_bit_cast(unsigned, f);
    u += 0x7FFFu + ((u >> 16) & 1u);
    return (u16)(u >> 16);
}
__device__ __forceinline__ float bf2f(u16 h) {
    return __builtin_bit_cast(float, ((unsigned)h) << 16);
}

#define GLOAD_LDS16(g, l)                                                     \
    __builtin_amdgcn_global_load_lds(                                         \
        (const __attribute__((address_space(1))) void*)(g),                   \
        (__attribute__((address_space(3))) void*)(l), 16, 0, 0)

// packed triangular index (u<=v), per segment
__device__ __forceinline__ int pk0(int a, int b) {
    int u = min(a, b), v = max(a, b);
    return u * 128 - (u * (u - 1)) / 2 + (v - u);
}
__device__ __forceinline__ int pk1(int a, int b) {
    int u = min(a, b), v = max(a, b);
    return BASE1 + u * 64 - (u * (u - 1)) / 2 + (v - u);
}
__device__ __forceinline__ int pk2(int a, int b) {
    int u = min(a, b), v = max(a, b);
    return BASE2 + u * 32 - (u * (u - 1)) / 2 + (v - u);
}

// ---------------------------------------------------------------- fused prep
// bid <  86    : uv table
// 86..1109     : transpose W1 (32x32 tiles, grid 32x32)
// 1110..1365   : transpose W2 (grid 8x32)
// 1366..2389   : convert W1
// 2390..2645   : convert W2
__device__ __forceinline__ void prep_transpose(const float* __restrict__ in, int C,
                                               u16* __restrict__ out, int ldOut,
                                               int bx, int by, int tid) {
    __shared__ float tile[32][33];
    int tr0 = by * 32, tc0 = bx * 32;
    int lr = tid >> 5, lc = tid & 31;
#pragma unroll
    for (int i = 0; i < 4; i++) {
        int rr = lr + i * 8;
        tile[rr][lc] = in[(size_t)(tr0 + rr) * C + tc0 + lc];
    }
    __syncthreads();
#pragma unroll
    for (int i = 0; i < 4; i++) {
        int rr = lr + i * 8;
        out[(size_t)(tc0 + rr) * ldOut + tr0 + lc] = f2bf(tile[lc][rr]);
    }
}
__device__ __forceinline__ void prep_convert(const float* __restrict__ in,
                                             u16* __restrict__ out, int i, int n4) {
    if (i >= n4) return;
    float4 v = ((const float4*)in)[i];
    union { u16 a[4]; unsigned long long q; } o;
    o.a[0] = f2bf(v.x); o.a[1] = f2bf(v.y); o.a[2] = f2bf(v.z); o.a[3] = f2bf(v.w);
    ((unsigned long long*)out)[i] = o.q;
}

__global__ __launch_bounds__(256) void k_prep(u16* __restrict__ tab,
                                              const float* __restrict__ W1,
                                              const float* __restrict__ W2,
                                              u16* __restrict__ W1b,
                                              u16* __restrict__ W1tb,
                                              u16* __restrict__ W2b,
                                              u16* __restrict__ W2tb) {
    int bid = blockIdx.x, tid = threadIdx.x;
    if (bid < 86) {
        int j = bid * 256 + tid;
        if (j < 16384) {
            int u = j >> 7, v = j & 127;
            if (v >= u) tab[pk0(u, v)] = (u16)((u << 7) | v);
        } else if (j < 20480) {
            int k = j - 16384, u = k >> 6, v = k & 63;
            if (v >= u) tab[pk1(u, v)] = (u16)((1 << 14) | (u << 7) | v);
        } else if (j < 21504) {
            int k = j - 20480, u = k >> 5, v = k & 31;
            if (v >= u) tab[pk2(u, v)] = (u16)((2 << 14) | (u << 7) | v);
        } else if (j < 21504 + (NPACK - NVALID)) {
            tab[NVALID + (j - 21504)] = 0xFFFFu;
        }
    } else if (bid < 1110) {
        int k = bid - 86;                       // grid 32x32
        prep_transpose(W1, 1024, W1tb, 1024, k & 31, k >> 5, tid);
    } else if (bid < 1366) {
        int k = bid - 1110;                     // grid 8x32
        prep_transpose(W2, 256, W2tb, 1024, k & 7, k >> 3, tid);
    } else if (bid < 2390) {
        prep_convert(W1, W1b, (bid - 1366) * 256 + tid, 1024 * 1024 / 4);
    } else {
        prep_convert(W2, W2b, (bid - 2390) * 256 + tid, 1024 * 256 / 4);
    }
}

// ---------------------------------------------------------------- packed weights
__global__ __launch_bounds__(256) void k_packw(const float* __restrict__ w0,
                                               const float* __restrict__ w1,
                                               const float* __restrict__ w2,
                                               const u16* __restrict__ tab,
                                               u16* __restrict__ Wsym,
                                               u16* __restrict__ Wt) {
    __shared__ u16 tile[32][258];
    __shared__ u16 te[32];
    int i0 = blockIdx.x * 32, h0 = blockIdx.y * 256, tid = threadIdx.x;
    if (tid < 32) te[tid] = tab[i0 + tid];
    __syncthreads();
    const float s1 = 0.57735026918962576f, s2 = 0.44721359549995794f;
    for (int il = 0; il < 32; il++) {
        unsigned e = te[il];
        float val = 0.f;
        if ((e >> 14) != 3) {
            int seg = e >> 14, u = (e >> 7) & 127, v = e & 127;
            const float* wb; int S; float sc;
            if (seg == 0)      { wb = w0; S = 128; sc = 1.f; }
            else if (seg == 1) { wb = w1; S = 64;  sc = s1; }
            else               { wb = w2; S = 32;  sc = s2; }
            val = sc * (wb[(size_t)(u * S + v) * 1024 + h0 + tid] +
                        wb[(size_t)(v * S + u) * 1024 + h0 + tid]);
        }
        u16 bv = f2bf(val);
        Wsym[(size_t)(i0 + il) * 1024 + h0 + tid] = bv;
        tile[il][tid] = bv;
    }
    __syncthreads();
    union { u16 a[32]; uint4 q[4]; } pk;
#pragma unroll
    for (int il = 0; il < 32; il++) pk.a[il] = tile[il][tid];
    uint4* dst = (uint4*)(Wt + (size_t)(h0 + tid) * NPACK + i0);
#pragma unroll
    for (int q = 0; q < 4; q++) dst[q] = pk.q[q];
}

// ---------------------------------------------------------------- packed features
__global__ __launch_bounds__(256) void k_features_pack(const float* __restrict__ t,
                                                       const u16* __restrict__ tab,
                                                       u16* __restrict__ P) {
    __shared__ u16 tab_s[NPACK];
    __shared__ float tr[480];
    int b = blockIdx.x, tid = threadIdx.x;
    for (int j = tid; j < NPACK / 8; j += 256)
        ((uint4*)tab_s)[j] = ((const uint4*)tab)[j];
    for (int j = tid; j < 480; j += 256) tr[j] = t[(size_t)b * 480 + j];
    __syncthreads();
    u16* row = P + (size_t)b * NPACK;
    for (int i = tid; i < NPACK; i += 256) {
        unsigned e = tab_s[i];
        float p = 0.f;
        if ((e >> 14) != 3) {
            int seg = e >> 14, u = (e >> 7) & 127, v = e & 127;
            if (seg == 0) p = tr[u] * tr[v];
            else if (seg == 1) {
                const float* x1 = tr + 128;
                p = x1[u*3]*x1[v*3] + x1[u*3+1]*x1[v*3+1] + x1[u*3+2]*x1[v*3+2];
            } else {
                const float* x2 = tr + 320;
#pragma unroll
                for (int m = 0; m < 5; m++) p += x2[u*5+m] * x2[v*5+m];
            }
            if (u == v) p *= 0.5f;
        }
        row[i] = f2bf(p);
    }
}

// ---------------------------------------------------------------- GEMM 128-tile (MLP sizes)
__global__ __launch_bounds__(256) void k_gemm2(const u16* __restrict__ A, int ldA,
                                               const u16* __restrict__ B, int ldB,
                                               int kLen, float scale,
                                               const float* __restrict__ bias,
                                               float* __restrict__ Cf,
                                               u16* __restrict__ Cb, int ldC,
                                               u16* __restrict__ Cpart, int Mtot,
                                               int swz) {
    __shared__ u16 As[2][128 * 32];
    __shared__ u16 Bs[2][128 * 32];
    const int tid = threadIdx.x;
    const int wave = tid >> 6, lane = tid & 63;
    const int wm = wave >> 1, wn = wave & 1;
    int nT, mT, z;
    if (swz == 1) {
        int L = blockIdx.x;
        z = L & 7; int r = L >> 3;
        nT = r >> 4; mT = r & 15;
    } else if (swz == 2) {
        int L = blockIdx.x;
        int c = L & 7, r = L >> 3;
        nT = (r % 11) * 8 + c; mT = r / 11; z = 0;
    } else {
        nT = blockIdx.x; mT = blockIdx.y; z = blockIdx.z;
    }
    const int m0 = mT * 128, n0 = nT * 128;
    const size_t kOff = (size_t)z * kLen;

    const int chl = (((lane & 3) ^ ((lane >> 3) & 3))) * 8;
    const u16* aG = A + (size_t)(m0 + wave * 32 + (lane >> 2)) * ldA + kOff + chl;
    const u16* bG = B + (size_t)(n0 + wave * 32 + (lane >> 2)) * ldB + kOff + chl;
    const size_t aS = (size_t)16 * ldA;
    const size_t bS = (size_t)16 * ldB;
    u16* aL0 = &As[0][(wave * 32) * 32];
    u16* aL1 = &As[0][(wave * 32 + 16) * 32];
    u16* aH0 = &As[1][(wave * 32) * 32];
    u16* aH1 = &As[1][(wave * 32 + 16) * 32];
    u16* bL0 = &Bs[0][(wave * 32) * 32];
    u16* bL1 = &Bs[0][(wave * 32 + 16) * 32];
    u16* bH0 = &Bs[1][(wave * 32) * 32];
    u16* bH1 = &Bs[1][(wave * 32 + 16) * 32];

    f32x4 acc[4][4];
#pragma unroll
    for (int i = 0; i < 4; i++)
#pragma unroll
        for (int j = 0; j < 4; j++) acc[i][j] = (f32x4){0.f, 0.f, 0.f, 0.f};

    const int ml = lane & 15, kq8 = lane >> 4;
    const int kqs = (kq8 ^ ((ml >> 1) & 3)) * 8;
    const u16* aRd0 = &As[0][(wm * 64 + ml) * 32 + kqs];
    const u16* bRd0 = &Bs[0][(wn * 64 + ml) * 32 + kqs];
    const u16* aRd1 = &As[1][(wm * 64 + ml) * 32 + kqs];
    const u16* bRd1 = &Bs[1][(wn * 64 + ml) * 32 + kqs];

    for (int k = 0; k < kLen; k += 64) {
        GLOAD_LDS16(aG, aL0);
        GLOAD_LDS16(aG + aS, aL1);
        GLOAD_LDS16(aG + 32, aH0);
        GLOAD_LDS16(aG + aS + 32, aH1);
        GLOAD_LDS16(bG, bL0);
        GLOAD_LDS16(bG + bS, bL1);
        GLOAD_LDS16(bG + 32, bH0);
        GLOAD_LDS16(bG + bS + 32, bH1);
        aG += 64; bG += 64;
        __syncthreads();
        {
            bf16x8 af[4], bfv[4];
#pragma unroll
            for (int i = 0; i < 4; i++) af[i]  = *(const bf16x8*)(aRd0 + i * 16 * 32);
#pragma unroll
            for (int j = 0; j < 4; j++) bfv[j] = *(const bf16x8*)(bRd0 + j * 16 * 32);
#pragma unroll
            for (int i = 0; i < 4; i++)
#pragma unroll
                for (int j = 0; j < 4; j++)
                    acc[i][j] = __builtin_amdgcn_mfma_f32_16x16x32_bf16(af[i], bfv[j], acc[i][j], 0, 0, 0);
        }
        {
            bf16x8 af[4], bfv[4];
#pragma unroll
            for (int i = 0; i < 4; i++) af[i]  = *(const bf16x8*)(aRd1 + i * 16 * 32);
#pragma unroll
            for (int j = 0; j < 4; j++) bfv[j] = *(const bf16x8*)(bRd1 + j * 16 * 32);
#pragma unroll
            for (int i = 0; i < 4; i++)
#pragma unroll
                for (int j = 0; j < 4; j++)
                    acc[i][j] = __builtin_amdgcn_mfma_f32_16x16x32_bf16(af[i], bfv[j], acc[i][j], 0, 0, 0);
        }
        __syncthreads();
    }

    const int q = lane >> 4, nl = lane & 15;
    if (Cpart) {
        u16* outP = Cpart + (size_t)z * Mtot * ldC;
#pragma unroll
        for (int i = 0; i < 4; i++)
#pragma unroll
            for (int j = 0; j < 4; j++)
#pragma unroll
                for (int reg = 0; reg < 4; reg++) {
                    int row = m0 + wm * 64 + i * 16 + q * 4 + reg;
                    int col = n0 + wn * 64 + j * 16 + nl;
                    outP[(size_t)row * ldC + col] = f2bf(acc[i][j][reg]);
                }
    } else {
#pragma unroll
        for (int i = 0; i < 4; i++)
#pragma unroll
            for (int j = 0; j < 4; j++)
#pragma unroll
                for (int reg = 0; reg < 4; reg++) {
                    int row = m0 + wm * 64 + i * 16 + q * 4 + reg;
                    int col = n0 + wn * 64 + j * 16 + nl;
                    float v = acc[i][j][reg] * scale + (bias ? bias[col] : 0.0f);
                    if (Cf) Cf[(size_t)row * ldC + col] = v;
                    else    Cb[(size_t)row * ldC + col] = f2bf(v);
                }
    }
}

// ---------------------------------------------------------------- GEMM 256-tile (GEMM1), R3 schedule
#define VMCNT0 asm volatile("s_waitcnt vmcnt(0)" ::: "memory")
#define BARX() __builtin_amdgcn_s_barrier()

#define STG_A(p, kh, rh, kb) GLOAD_LDS16(aB + (size_t)(rh) * aH + (kb) + (kh) * 32, \
                                         &As[p][kh][((rh) * 128 + wave * 16) * 32])
#define STG_B(p, kh, rh, kb) GLOAD_LDS16(bB + (size_t)(rh) * bH + (kb) + (kh) * 32, \
                                         &Bs[p][kh][((rh) * 128 + wave * 16) * 32])
#define MMQ(fb, gb, bv) do { _Pragma("unroll") \
    for (int ff = 0; ff < 4; ff++) { _Pragma("unroll") \
        for (int gg = 0; gg < 2; gg++) { \
            acc[(fb)+ff][(gb)+gg] = __builtin_amdgcn_mfma_f32_16x16x32_bf16(a[2*ff],   bv[2*gg],   acc[(fb)+ff][(gb)+gg], 0, 0, 0); \
            acc[(fb)+ff][(gb)+gg] = __builtin_amdgcn_mfma_f32_16x16x32_bf16(a[2*ff+1], bv[2*gg+1], acc[(fb)+ff][(gb)+gg], 0, 0, 0); } } } while (0)

__global__ __launch_bounds__(512, 2) void k_gemm256(const u16* __restrict__ A, int ldA,
                                                    const u16* __restrict__ B, int ldB,
                                                    int kLen, float scale,
                                                    const float* __restrict__ bias,
                                                    u16* __restrict__ Cb, int ldC,
                                                    u16* __restrict__ Cpart, int Mtot,
                                                    int swz) {
    __shared__ __align__(16) u16 As[2][2][256 * 32];   // [buf][kh][row*32+k]  64 KB
    __shared__ __align__(16) u16 Bs[2][2][256 * 32];   // 64 KB
    const int tid = threadIdx.x;
    const int lane = tid & 63, wave = tid >> 6;
    const int wm = wave >> 2, wn = wave & 3;
    int mT, nT, z;
    if (swz == 1) {
        // GEMM1: 256 blocks. XCD = z = L&7. Within XCD: nT fastest.
        z = blockIdx.x & 7; int r = blockIdx.x >> 3; nT = r & 3; mT = r >> 2;
    } else {
        int x = blockIdx.x & 7, j = blockIdx.x >> 3;
        int nti = j >> 3; mT = j & 7;
        if (nti < 5)      nT = nti * 8 + x;
        else if (x < 4)   nT = 40 + x;
        else            { nT = 40 + (x - 4); mT = (j & 7) + 4; }
        z = 0;
    }
    const int m0 = mT * 256, n0 = nT * 256;
    const size_t kOff = (size_t)z * kLen;
    const int nTi = kLen >> 6;          // K-64 tiles, >= 2

    const int chl = ((tid & 3) ^ ((tid >> 3) & 3)) * 8;
    const u16* aB = A + (size_t)(m0 + (tid >> 2)) * ldA + kOff + chl;
    const u16* bB = B + (size_t)(n0 + (tid >> 2)) * ldB + kOff + chl;
    const size_t aH = (size_t)128 * ldA;
    const size_t bH = (size_t)128 * ldB;

    const int ml = lane & 15, kq8 = lane >> 4;
    const int kqs = (kq8 ^ ((ml >> 1) & 3)) * 8;
    const int aro = (wm * 128 + ml) * 32 + kqs;
    const int bro = (wn * 64 + ml) * 32 + kqs;

    f32x4 acc[8][4];
#pragma unroll
    for (int f = 0; f < 8; f++)
#pragma unroll
        for (int g = 0; g < 4; g++) acc[f][g] = (f32x4){0.f, 0.f, 0.f, 0.f};
    bf16x8 a[8], b[4], b2[4];

    STG_A(0, 0, 0, 0); STG_A(0, 0, 1, 0); STG_A(0, 1, 0, 0); STG_A(0, 1, 1, 0);
    STG_B(0, 0, 0, 0); STG_B(0, 0, 1, 0); STG_B(0, 1, 0, 0); STG_B(0, 1, 1, 0);
    VMCNT0;
    BARX();

    for (int t = 0; t < nTi; t++) {
        const int p = t & 1, p1 = p ^ 1;
        const int kb1 = (t + 1) << 6;
        const bool s1 = (t + 1) < nTi;
        // phase 0
#pragma unroll
        for (int f = 0; f < 4; f++) {
            a[2*f]   = *(const bf16x8*)&As[p][0][aro + f * 512];
            a[2*f+1] = *(const bf16x8*)&As[p][1][aro + f * 512];
        }
#pragma unroll
        for (int g = 0; g < 2; g++) {
            b[2*g]   = *(const bf16x8*)&Bs[p][0][bro + g * 512];
            b[2*g+1] = *(const bf16x8*)&Bs[p][1][bro + g * 512];
        }
        if (s1) { STG_A(p1, 0, 0, kb1); STG_A(p1, 0, 1, kb1); }
        BARX();
        __builtin_amdgcn_s_setprio(1);
        MMQ(0, 0, b);
        __builtin_amdgcn_s_setprio(0);
        BARX();
        // phase 1
#pragma unroll
        for (int g = 0; g < 2; g++) {
            b2[2*g]   = *(const bf16x8*)&Bs[p][0][bro + (g + 2) * 512];
            b2[2*g+1] = *(const bf16x8*)&Bs[p][1][bro + (g + 2) * 512];
        }
        if (s1) { STG_A(p1, 1, 0, kb1); STG_A(p1, 1, 1, kb1); }
        BARX();
        __builtin_amdgcn_s_setprio(1);
        MMQ(0, 2, b2);
        __builtin_amdgcn_s_setprio(0);
        BARX();
        // phase 2
#pragma unroll
        for (int f = 0; f < 4; f++) {
            a[2*f]   = *(const bf16x8*)&As[p][0][aro + (f + 4) * 512];
            a[2*f+1] = *(const bf16x8*)&As[p][1][aro + (f + 4) * 512];
        }
        if (s1) { STG_B(p1, 0, 0, kb1); STG_B(p1, 0, 1, kb1); }
        BARX();
        __builtin_amdgcn_s_setprio(1);
        MMQ(4, 0, b);
        __builtin_amdgcn_s_setprio(0);
        BARX();
        // phase 3
        if (s1) { STG_B(p1, 1, 0, kb1); STG_B(p1, 1, 1, kb1); }
        __builtin_amdgcn_s_setprio(1);
        MMQ(4, 2, b2);
        __builtin_amdgcn_s_setprio(0);
        if (s1) VMCNT0;
        BARX();
    }

    const int q = lane >> 4, nl = lane & 15;
    if (Cpart) {
        u16* outP = Cpart + (size_t)z * Mtot * ldC;
#pragma unroll
        for (int f = 0; f < 8; f++)
#pragma unroll
            for (int g = 0; g < 4; g++)
#pragma unroll
                for (int reg = 0; reg < 4; reg++) {
                    int row = m0 + wm * 128 + f * 16 + q * 4 + reg;
                    int col = n0 + wn * 64 + g * 16 + nl;
                    outP[(size_t)row * ldC + col] = f2bf(acc[f][g][reg]);
                }
    } else {
#pragma unroll
        for (int f = 0; f < 8; f++)
#pragma unroll
            for (int g = 0; g < 4; g++)
#pragma unroll
                for (int reg = 0; reg < 4; reg++) {
                    int row = m0 + wm * 128 + f * 16 + q * 4 + reg;
                    int col = n0 + wn * 64 + g * 16 + nl;
                    float v = acc[f][g][reg] * scale + (bias ? bias[col] : 0.0f);
                    Cb[(size_t)row * ldC + col] = f2bf(v);
                }
    }
}

// ---------------------------------------------------------------- GEMM 128x256-tile (GEMM2)
#define MMQ22(fb, gb, bv) do { _Pragma("unroll") \
    for (int ff = 0; ff < 2; ff++) { _Pragma("unroll") \
        for (int gg = 0; gg < 2; gg++) { \
            acc[(fb)+ff][(gb)+gg] = __builtin_amdgcn_mfma_f32_16x16x32_bf16(a[2*ff],   bv[2*gg],   acc[(fb)+ff][(gb)+gg], 0, 0, 0); \
            acc[(fb)+ff][(gb)+gg] = __builtin_amdgcn_mfma_f32_16x16x32_bf16(a[2*ff+1], bv[2*gg+1], acc[(fb)+ff][(gb)+gg], 0, 0, 0); } } } while (0)

__global__ __launch_bounds__(512, 2) void k_gemm128n(const u16* __restrict__ A, int ldA,
                                                     const u16* __restrict__ B, int ldB,
                                                     int kLen, float scale,
                                                     u16* __restrict__ Cb, int ldC) {
    __shared__ __align__(16) u16 As[2][2][128 * 32];   // [buf][kh] 32 KB total
    __shared__ __align__(16) u16 Bs[2][2][256 * 32];   // 64 KB
    const int tid = threadIdx.x;
    const int lane = tid & 63, wave = tid >> 6;
    const int wm = wave >> 2, wn = wave & 3;           // wm 0..1, wn 0..3
    int x = blockIdx.x & 7, j = blockIdx.x >> 3;
    int nti = j >> 4, mT = j & 15, nT;
    if (nti < 5) nT = nti * 8 + x;
    else { nT = 40 + (x & 3); mT = (j & 7) + 8 * (x >> 2); }
    const int m0 = mT * 128, n0 = nT * 256;
    const int nTi = kLen >> 6;

    const int chl = ((tid & 3) ^ ((tid >> 3) & 3)) * 8;
    const u16* aB = A + (size_t)(m0 + (tid >> 2)) * ldA + chl;   // rows 0..127
    const u16* bB = B + (size_t)(n0 + (tid >> 2)) * ldB + chl;
    const size_t bH = (size_t)128 * ldB;

    const int ml = lane & 15, kq8 = lane >> 4;
    const int kqs = (kq8 ^ ((ml >> 1) & 3)) * 8;
    const int aro = (wm * 64 + ml) * 32 + kqs;
    const int bro = (wn * 64 + ml) * 32 + kqs;

    f32x4 acc[4][4];
#pragma unroll
    for (int f = 0; f < 4; f++)
#pragma unroll
        for (int g = 0; g < 4; g++) acc[f][g] = (f32x4){0.f, 0.f, 0.f, 0.f};
    bf16x8 a[4], b[4], b2[4];

#define SG_A(p, kh, kb) GLOAD_LDS16(aB + (kb) + (kh) * 32, &As[p][kh][(wave * 16) * 32])
#define SG_B(p, kh, rh, kb) GLOAD_LDS16(bB + (size_t)(rh) * bH + (kb) + (kh) * 32, \
                                        &Bs[p][kh][((rh) * 128 + wave * 16) * 32])

    SG_A(0, 0, 0); SG_A(0, 1, 0);
    SG_B(0, 0, 0, 0); SG_B(0, 0, 1, 0); SG_B(0, 1, 0, 0); SG_B(0, 1, 1, 0);
    VMCNT0;
    BARX();

    for (int t = 0; t < nTi; t++) {
        const int p = t & 1, p1 = p ^ 1;
        const int kb1 = (t + 1) << 6;
        const bool s1 = (t + 1) < nTi;
        // phase 0: a f0..1, b g0..1; stage t+1 A kh0+kh1
#pragma unroll
        for (int f = 0; f < 2; f++) {
            a[2*f]   = *(const bf16x8*)&As[p][0][aro + f * 512];
            a[2*f+1] = *(const bf16x8*)&As[p][1][aro + f * 512];
        }
#pragma unroll
        for (int g = 0; g < 2; g++) {
            b[2*g]   = *(const bf16x8*)&Bs[p][0][bro + g * 512];
            b[2*g+1] = *(const bf16x8*)&Bs[p][1][bro + g * 512];
        }
        if (s1) { SG_A(p1, 0, kb1); SG_A(p1, 1, kb1); }
        BARX();
        __builtin_amdgcn_s_setprio(1);
        MMQ22(0, 0, b);
        __builtin_amdgcn_s_setprio(0);
        BARX();
        // phase 1: b2 g2..3; stage t+1 B kh0
#pragma unroll
        for (int g = 0; g < 2; g++) {
            b2[2*g]   = *(const bf16x8*)&Bs[p][0][bro + (g + 2) * 512];
            b2[2*g+1] = *(const bf16x8*)&Bs[p][1][bro + (g + 2) * 512];
        }
        if (s1) { SG_B(p1, 0, 0, kb1); SG_B(p1, 0, 1, kb1); }
        BARX();
        __builtin_amdgcn_s_setprio(1);
        MMQ22(0, 2, b2);
        __builtin_amdgcn_s_setprio(0);
        BARX();
        // phase 2: a f2..3; stage t+1 B kh1
#pragma unroll
        for (int f = 0; f < 2; f++) {
            a[2*f]   = *(const bf16x8*)&As[p][0][aro + (f + 2) * 512];
            a[2*f+1] = *(const bf16x8*)&As[p][1][aro + (f + 2) * 512];
        }
        if (s1) { SG_B(p1, 1, 0, kb1); SG_B(p1, 1, 1, kb1); }
        BARX();
        __builtin_amdgcn_s_setprio(1);
        MMQ22(2, 0, b);
        __builtin_amdgcn_s_setprio(0);
        BARX();
        // phase 3: no reads/stages; tile-boundary drain
        __builtin_amdgcn_s_setprio(1);
        MMQ22(2, 2, b2);
        __builtin_amdgcn_s_setprio(0);
        if (s1) VMCNT0;
        BARX();
    }

    const int q = lane >> 4, nl = lane & 15;
#pragma unroll
    for (int f = 0; f < 4; f++)
#pragma unroll
        for (int g = 0; g < 4; g++)
#pragma unroll
            for (int reg = 0; reg < 4; reg++) {
                int row = m0 + wm * 64 + f * 16 + q * 4 + reg;
                int col = n0 + wn * 64 + g * 16 + nl;
                Cb[(size_t)row * ldC + col] = f2bf(acc[f][g][reg] * scale);
            }
}

// sum split-K bf16 partials + epilogue
__global__ __launch_bounds__(256) void k_reduce(const u16* __restrict__ part, size_t stride,
                                                int SK, int total, int N, float scale,
                                                const float* __restrict__ bias,
                                                float* __restrict__ outF, u16* __restrict__ outB) {
    int i = blockIdx.x * 256 + threadIdx.x;
    if (i >= total) return;
    float s = 0.f;
    for (int z = 0; z < SK; z++) s += bf2f(part[(size_t)z * stride + i]);
    float v = s * scale + (bias ? bias[i % N] : 0.0f);
    if (outF) outF[i] = v;
    else      outB[i] = f2bf(v);
}

// ---------------------------------------------------------------- rowwise LN
__device__ __forceinline__ float blockReduce(float v, float* red) {
#pragma unroll
    for (int off = 32; off > 0; off >>= 1) v += __shfl_down(v, off);
    __syncthreads();
    if ((threadIdx.x & 63) == 0) red[threadIdx.x >> 6] = v;
    __syncthreads();
    return red[0] + red[1] + red[2] + red[3];
}

__global__ __launch_bounds__(256) void k_ln_fwd(const float* __restrict__ X, int D,
    const float* __restrict__ g, const float* __restrict__ be,
    float* __restrict__ mu_out, float* __restrict__ r_out,
    u16* __restrict__ a_bf, float* __restrict__ a_f32) {
    __shared__ float red[4];
    int b = blockIdx.x, tid = threadIdx.x;
    const float* x = X + (size_t)b * D;
    int nd = D >> 8;
    float s = 0.f, s2 = 0.f;
    for (int r = 0; r < nd; r++) { float v = x[tid + (r << 8)]; s += v; s2 += v * v; }
    s = blockReduce(s, red);
    s2 = blockReduce(s2, red);
    float mu = s / D;
    float var = s2 / D - mu * mu;
    float rst = rsqrtf(var + 1e-6f);
    if (tid == 0) { mu_out[b] = mu; r_out[b] = rst; }
    for (int r = 0; r < nd; r++) {
        int i = tid + (r << 8);
        float xh = (x[i] - mu) * rst;
        float ln = xh * g[i] + be[i];
        float a = ln / (1.0f + expf(-ln));
        if (a_bf)  a_bf[(size_t)b * D + i] = f2bf(a);
        if (a_f32) a_f32[(size_t)b * D + i] = a;
    }
}

__global__ __launch_bounds__(256) void k_ln_bwd(const float* __restrict__ dup,
    const float* __restrict__ X, const float* __restrict__ mu_in, const float* __restrict__ r_in,
    const float* __restrict__ g, const float* __restrict__ be,
    u16* __restrict__ out_bf, int D) {
    __shared__ float red[4];
    int b = blockIdx.x, tid = threadIdx.x;
    const float* x = X + (size_t)b * D;
    float mu = mu_in[b], rst = r_in[b];
    int nd = D >> 8;
    float w_[4], xh_[4];
    float sw = 0.f, swx = 0.f;
    for (int r = 0; r < nd; r++) {
        int i = tid + (r << 8);
        float xh = (x[i] - mu) * rst;
        float ln = xh * g[i] + be[i];
        float sg = 1.0f / (1.0f + expf(-ln));
        float dsilu = sg * (1.0f + ln * (1.0f - sg));
        float d = dup ? dup[(size_t)b * D + i] : 1.0f;
        float w = g[i] * dsilu * d;
        w_[r] = w; xh_[r] = xh;
        sw += w; swx += w * xh;
    }
    sw = blockReduce(sw, red);
    swx = blockReduce(swx, red);
    float invD = 1.0f / D;
    for (int r = 0; r < nd; r++) {
        int i = tid + (r << 8);
        float dx = rst * (w_[r] - sw * invD - xh_[r] * swx * invD);
        out_bf[(size_t)b * D + i] = f2bf(dx);
    }
}

// ---------------------------------------------------------------- packed contraction
// y[b,a] = sum_v Gsym[a,v] x[v]. Shuffle-free: per-thread-owned outputs with
// serial accumulation over a v-range + one small LDS combine per segment.
// (Old version ran a 6-deep dependent __shfl chain per output: ~720 serialized
// crossbar ops/wave -> 80 us latency-bound. This is ~132 independent FMAs/thread.)
__global__ __launch_bounds__(256) void k_contract_p(const u16* __restrict__ Gp,
                                                    const float* __restrict__ t,
                                                    float* __restrict__ y) {
    __shared__ u16 gp_s[NPACK];
    __shared__ float xs[480];
    __shared__ float red[1280];
    int b = blockIdx.x, tid = threadIdx.x;
    const uint4* gsrc = (const uint4*)(Gp + (size_t)b * NPACK);
    for (int j = tid; j < NPACK / 8; j += 256) ((uint4*)gp_s)[j] = gsrc[j];
    for (int j = tid; j < 480; j += 256) xs[j] = t[(size_t)b * 480 + j];
    __syncthreads();
    float* yr = y + (size_t)b * 480;

    // seg0: 128 outputs x 128 terms. thread = (u, half): 64 MACs, 2-way combine.
    {
        int u = tid & 127, half = tid >> 7;
        int v0 = half * 64;
        float s = 0.f;
#pragma unroll 8
        for (int i = 0; i < 64; i++) {
            int v = v0 + i;
            s += bf2f(gp_s[pk0(u, v)]) * xs[v];
        }
        red[tid] = s;
    }
    __syncthreads();
    if (tid < 128) yr[tid] = red[tid] + red[tid + 128];
    __syncthreads();

    // seg1: 64 outputs x 3 m x 64 terms. thread = (u, q): 16 v, 4-way combine.
    {
        int u = tid & 63, q = tid >> 6;
        int v0 = q * 16;
        float a0 = 0.f, a1 = 0.f, a2 = 0.f;
#pragma unroll 4
        for (int i = 0; i < 16; i++) {
            int v = v0 + i;
            float gv = bf2f(gp_s[pk1(u, v)]);
            a0 += gv * xs[128 + v * 3 + 0];
            a1 += gv * xs[128 + v * 3 + 1];
            a2 += gv * xs[128 + v * 3 + 2];
        }
        int base = (u * 4 + q) * 3;
        red[base + 0] = a0; red[base + 1] = a1; red[base + 2] = a2;
    }
    __syncthreads();
    if (tid < 192) {
        int u = tid / 3, m = tid - u * 3;
        float s = 0.f;
#pragma unroll
        for (int q = 0; q < 4; q++) s += red[(u * 4 + q) * 3 + m];
        yr[128 + u * 3 + m] = s;
    }
    __syncthreads();

    // seg2: 32 outputs x 5 m x 32 terms. thread = (u, o): 4 v, 8-way combine.
    {
        int u = tid & 31, o = tid >> 5;
        int v0 = o * 4;
        float a[5] = {0.f, 0.f, 0.f, 0.f, 0.f};
#pragma unroll
        for (int i = 0; i < 4; i++) {
            int v = v0 + i;
            float gv = bf2f(gp_s[pk2(u, v)]);
#pragma unroll
            for (int m = 0; m < 5; m++) a[m] += gv * xs[320 + v * 5 + m];
        }
        int base = (u * 8 + o) * 5;
#pragma unroll
        for (int m = 0; m < 5; m++) red[base + m] = a[m];
    }
    __syncthreads();
    if (tid < 160) {
        int u = tid / 5, m = tid - u * 5;
        float s = 0.f;
#pragma unroll
        for (int o = 0; o < 8; o++) s += red[(u * 8 + o) * 5 + m];
        yr[320 + u * 5 + m] = s;
    }
}

// ---------------------------------------------------------------- launch
extern "C" void kernel_launch(void* const* d_in, const int* in_sizes, int n_in,
                              void* d_out, int out_size, void* d_ws, size_t ws_size,
                              hipStream_t stream) {
    const float* t   = (const float*)d_in[0];
    const float* w0  = (const float*)d_in[1];
    const float* w1  = (const float*)d_in[2];
    const float* w2  = (const float*)d_in[3];
    const float* W1  = (const float*)d_in[4];
    const float* b1  = (const float*)d_in[5];
    const float* g1  = (const float*)d_in[6];
    const float* be1 = (const float*)d_in[7];
    const float* W2  = (const float*)d_in[8];
    const float* b2  = (const float*)d_in[9];
    const float* g2  = (const float*)d_in[10];
    const float* be2 = (const float*)d_in[11];

    float* xout = (float*)d_out;                    // 2048*256
    float* yout = xout + (size_t)2048 * 256;        // 2048*480

    char* ws = (char*)d_ws;
    size_t off = 0;
    auto alloc = [&](size_t bytes) -> void* {
        void* p = ws + off;
        off += (bytes + 255) & ~(size_t)255;
        return p;
    };
    u16*   PG    = (u16*)alloc((size_t)2048 * NPACK * 2);   // Ppack, later Gp (aliased)
    u16*   Wsym  = (u16*)alloc((size_t)NPACK * 1024 * 2);   // packed Wsym [i,h]
    u16*   Wt    = (u16*)alloc((size_t)1024 * NPACK * 2);   // packed Wsym^T [h,i]
    u16*   uvtab = (u16*)alloc((size_t)NPACK * 2);
    u16*   W1b   = (u16*)alloc((size_t)1024 * 1024 * 2);
    u16*   W1tb  = (u16*)alloc((size_t)1024 * 1024 * 2);
    u16*   W2b   = (u16*)alloc((size_t)1024 * 256 * 2);
    u16*   W2tb  = (u16*)alloc((size_t)256 * 1024 * 2);
    u16*   h_bf  = (u16*)alloc((size_t)2048 * 1024 * 2);
    float* h1pre = (float*)alloc((size_t)2048 * 1024 * 4);
    float* mu1   = (float*)alloc(2048 * 4);
    float* r1    = (float*)alloc(2048 * 4);
    u16*   a1_bf = (u16*)alloc((size_t)2048 * 1024 * 2);
    float* h2pre = (float*)alloc((size_t)2048 * 256 * 4);
    float* mu2   = (float*)alloc(2048 * 4);
    float* r2    = (float*)alloc(2048 * 4);
    u16*   dh2b  = (u16*)alloc((size_t)2048 * 256 * 2);
    float* d_a1  = (float*)alloc((size_t)2048 * 1024 * 4);
    u16*   dh1b  = (u16*)alloc((size_t)2048 * 1024 * 2);
    u16*   de_bf = (u16*)alloc((size_t)2048 * 1024 * 2);
    u16*   Cpart = (u16*)(ws + off);
    size_t cpartBytes = (ws_size > off) ? (ws_size - off) : 0;
    (void)in_sizes; (void)n_in; (void)out_size;

    const float sF = 1.0f / sqrtf(21504.0f);

    // generic GEMM helper (MLP GEMMs): 3-D grid, optional split-K (bf16 partials)
    auto gemm = [&](const u16* A, int ldA, const u16* B, int ldB, int M, int N, int K,
                    int SKwant, float scale, const float* bias,
                    float* Cf, u16* Cb, int ldC) {
        int SK = SKwant;
        size_t slice = (size_t)M * ldC * 2;
        if (SK > 1 && cpartBytes < 2 * slice) SK = 1;
        if (SK > 1 && (size_t)SK * slice > cpartBytes) SK = (int)(cpartBytes / slice);
        while (SK > 1 && !((K % SK) == 0 && ((K / SK) % 64) == 0)) SK--;
        dim3 grid(N / 128, M / 128, SK);
        if (SK > 1) {
            k_gemm2<<<grid, 256, 0, stream>>>(A, ldA, B, ldB, K / SK, 0.f, nullptr,
                                              nullptr, nullptr, ldC, Cpart, M, 0);
            int total = M * ldC;
            k_reduce<<<(total + 255) / 256, 256, 0, stream>>>(Cpart, (size_t)M * ldC, SK,
                                                              total, N, scale, bias, Cf, Cb);
        } else {
            k_gemm2<<<grid, 256, 0, stream>>>(A, ldA, B, ldB, K, scale, bias,
                                              Cf, Cb, ldC, nullptr, M, 0);
        }
    };

    // fused prep: uv table + W transposes + W converts (one launch)
    k_prep<<<2646, 256, 0, stream>>>(uvtab, W1, W2, W1b, W1tb, W2b, W2tb);
    // packed weights (needs uvtab)
    k_packw<<<dim3(NPACK / 32, 4), 256, 0, stream>>>(w0, w1, w2, uvtab, Wsym, Wt);

    // packed features
    k_features_pack<<<2048, 256, 0, stream>>>(t, uvtab, PG);

    // GEMM1: h = sF * Ppack @ Wt^T. 256-tile: 8z x (4nT x 8mT) = 256 blocks, kLen=1408.
    k_gemm256<<<dim3(256), 512, 0, stream>>>(PG, NPACK, Wt, NPACK, NPACK / 8, 0.f, nullptr,
                                             nullptr, 1024, Cpart, 2048, 1);
    {
        int total = 2048 * 1024;
        k_reduce<<<(total + 255) / 256, 256, 0, stream>>>(Cpart, (size_t)2048 * 1024, 8,
                                                          total, 1024, sF, nullptr,
                                                          nullptr, h_bf);
    }

    // MLP forward
    gemm(h_bf, 1024, W1tb, 1024, 2048, 1024, 1024, 4, 1.0f, b1, h1pre, nullptr, 1024);
    k_ln_fwd<<<2048, 256, 0, stream>>>(h1pre, 1024, g1, be1, mu1, r1, a1_bf, nullptr);
    gemm(a1_bf, 1024, W2tb, 1024, 2048, 256, 1024, 8, 1.0f, b2, h2pre, nullptr, 256);
    k_ln_fwd<<<2048, 256, 0, stream>>>(h2pre, 256, g2, be2, mu2, r2, nullptr, xout);

    // backward
    k_ln_bwd<<<2048, 256, 0, stream>>>(nullptr, h2pre, mu2, r2, g2, be2, dh2b, 256);
    gemm(dh2b, 256, W2b, 256, 2048, 1024, 256, 4, 1.0f, nullptr, d_a1, nullptr, 1024);
    k_ln_bwd<<<2048, 256, 0, stream>>>(d_a1, h1pre, mu1, r1, g1, be1, dh1b, 1024);
    gemm(dh1b, 1024, W1b, 1024, 2048, 1024, 1024, 4, sF, nullptr, nullptr, de_bf, 1024);

    // GEMM2: Gp = de @ Wsym^T. 128x256-tile: 704 blocks (~2.75 balanced rounds).
    u16* Gp = PG;   // Ppack dead after GEMM1
    k_gemm128n<<<dim3(704), 512, 0, stream>>>(de_bf, 1024, Wsym, 1024, 1024, 1.0f,
                                              Gp, NPACK);

    // y from packed symmetric Gp (shuffle-free contraction)
    k_contract_p<<<2048, 256, 0, stream>>>(Gp, t, yout);
}